// Round 5
// baseline (3918.393 us; speedup 1.0000x reference)
//
#include <hip/hip_runtime.h>
#include <hip/hip_cooperative_groups.h>
namespace cg = cooperative_groups;

#define NB 512      // batch
#define NK 1152     // input capsules
#define ND 8        // in dim
#define NU 16       // out dim
#define NJ 10       // output capsules
#define EPSQ 1e-7f

// ---- fused (cooperative) tiling: 32 kc-chunks x 36 k, 16 b-groups x 32 b ----
#define KC2 32
#define KT2 36
#define BGN2 16
#define BT2 32
#define XPITCH 268   // x row: b*8 + (b>>3)*4 swizzle -> conflict-free / 2-way
#define WKP2 140     // w row: pair p at p*16 + (p>>1)*4 (+8 for odd u)
#define SREDP 18     // padded [32][18] union sv(b*16+u) / sfinal(b*18+u)

// ---- R4 fallback tiling ----
#define KC 18
#define BGN 32
#define XP 516
#define WKP 164
#define XAP 132

// ws layout (floats)
#define OFF_BL 0                           // b_logits [NK][NJ]        11520
#define OFF_P2 11520                       // fused partial [KC2][NB][NU] 262144
#define OFF_C  (OFF_P2 + KC2*NB*NU)        // fallback cg [NK]
#define OFF_AGP (OFF_C + NK)               // fallback agp [NK][BGN]
#define OFF_P1 (OFF_AGP + NK*BGN)          // fallback partial [KC][NB][NU]
#define OFF_WT (OFF_P1 + KC*NB*NU)         // WT [NJ][NK][NU][ND]
#define WT_FLOATS (NJ*NK*NU*ND)            // 1474560 (~7.7 MB total, ws is huge)

#define WOFF(u) ((((u) >> 1) << 4) + ((((u) >> 1) >> 1) << 2) + (((u) & 1) << 3))

// ---------------------------------------------------------------------------
// init: zero b_logits, build WT[j][k][u][d] = W[j][k][d][u]
// ---------------------------------------------------------------------------
__global__ __launch_bounds__(256) void caps_init(const float* __restrict__ W,
                                                 float* __restrict__ bl,
                                                 float* __restrict__ WT) {
  int idx = blockIdx.x * 256 + threadIdx.x;
  if (idx < NK * NJ) bl[idx] = 0.f;
  if (idx < WT_FLOATS) {
    int d = idx & 7;
    int u = (idx >> 3) & 15;
    int k = (idx >> 7) % NK;
    int j = idx / (NK * NU * ND);
    WT[idx] = W[((size_t)(j * NK + k) * ND + d) * NU + u];
  }
}

// ===========================================================================
//                      FUSED COOPERATIVE KERNEL
// ===========================================================================
__device__ __forceinline__ void stage_w(float* sw, const float* WT, int j,
                                        int k0, int tid) {
  const float4* gw = (const float4*)(WT + ((size_t)j * NK + k0) * (NU * ND));
  for (int i = tid; i < KT2 * 32; i += 256) {
    const int k = i >> 5, r = i & 31;
    const int u = r >> 1, h = r & 1;
    const float4 vw = gw[i];
    *(float4*)&sw[k * WKP2 + WOFF(u) + h * 4] = vw;
  }
}

// phase A: v = squash(sum_kc partial) (all blocks, for own bgi);
// optional out write (kc==0); optional agree -> atomicAdd bl[k][ja].
__device__ __forceinline__ void phaseA(const float* sx, const float* sw,
                                       float* svred, const float* partial,
                                       float* bl, float* out, int b0, int k0,
                                       int ja, int wout, int do_agree,
                                       int tid) {
#pragma unroll
  for (int p = 0; p < 2; ++p) {
    const int b = p * 16 + (tid >> 4);     // wave = 4 b x 16 u; u = low 4 bits
    const int u = tid & 15;
    const float* pp = partial + (size_t)(b0 + b) * NU + u;
    float s = 0.f;
#pragma unroll
    for (int c = 0; c < KC2; ++c) s += pp[(size_t)c * (NB * NU)];
    float sq = s * s;
    sq += __shfl_xor(sq, 1, 64);
    sq += __shfl_xor(sq, 2, 64);
    sq += __shfl_xor(sq, 4, 64);
    sq += __shfl_xor(sq, 8, 64);
    const float scale = (sq / (1.f + sq)) / (sqrtf(sq) + EPSQ);
    const float vv = scale * s;
    svred[b * 16 + u] = vv;                // sv view, pitch 16
    if (wout) out[((size_t)(b0 + b) * NJ + ja) * NU + u] = vv;
  }
  __syncthreads();
  if (!do_agree) return;
  const int wv = tid >> 6;
  const int lane = tid & 63;
  const int u = lane & 15;
  const int bs = lane >> 4;
  const float* wcol = sw + WOFF(u);
  for (int kk = 0; kk < 9; ++kk) {         // wave owns 9 k's
    const int kl = wv * 9 + kk;
    const float* wr = wcol + kl * WKP2;
    const float4 wa = *(const float4*)wr;
    const float4 wb = *(const float4*)(wr + 4);
    float a = 0.f;
#pragma unroll
    for (int i = 0; i < 8; ++i) {
      const int b = bs * 8 + i;
      const float* xr = sx + kl * XPITCH + b * 8 + ((b >> 3) << 2);
      const float4 xa = *(const float4*)xr;
      const float4 xb = *(const float4*)(xr + 4);
      float dot = xa.x * wa.x + xa.y * wa.y + xa.z * wa.z + xa.w * wa.w +
                  xb.x * wb.x + xb.y * wb.y + xb.z * wb.z + xb.w * wb.w;
      a = fmaf(svred[b * 16 + u], dot, a);
    }
    a += __shfl_xor(a, 16, 64);            // over bs
    a += __shfl_xor(a, 32, 64);
    a += __shfl_xor(a, 1, 64);             // over u
    a += __shfl_xor(a, 2, 64);
    a += __shfl_xor(a, 4, 64);
    a += __shfl_xor(a, 8, 64);
    if (lane == 0) atomicAdd(&bl[(size_t)(k0 + kl) * NJ + ja], a);
  }
}

// phase B: s-partials for column j; lane = 4b x 2u micro-tile over wave's 9 k;
// cross-wave reduce via LDS float atomics; write partial[kc].
__device__ __forceinline__ void phaseB(const float* sx, const float* sw,
                                       const float* sc, float* svred,
                                       float* partial, int b0, int kc,
                                       int tid) {
  const int wv = tid >> 6;
  const int lane = tid & 63;
  const int bqg = lane & 7;
  const int ug = lane >> 3;
  float a0[4], a1[4];
#pragma unroll
  for (int i = 0; i < 4; ++i) { a0[i] = 0.f; a1[i] = 0.f; }
  const float* wpair = sw + WOFF(2 * ug);
  for (int kk = 0; kk < 9; ++kk) {
    const int kl = wv * 9 + kk;
    const float ck = sc[kl];
    const float* wr = wpair + kl * WKP2;
    const float4 w0 = *(const float4*)wr;
    const float4 w0b = *(const float4*)(wr + 4);
    const float4 w1 = *(const float4*)(wr + 8);
    const float4 w1b = *(const float4*)(wr + 12);
#pragma unroll
    for (int i = 0; i < 4; ++i) {
      const int b = bqg * 4 + i;
      const float* xr = sx + kl * XPITCH + b * 8 + ((b >> 3) << 2);
      const float4 xa = *(const float4*)xr;
      const float4 xb = *(const float4*)(xr + 4);
      float d0 = xa.x * w0.x + xa.y * w0.y + xa.z * w0.z + xa.w * w0.w +
                 xb.x * w0b.x + xb.y * w0b.y + xb.z * w0b.z + xb.w * w0b.w;
      float d1 = xa.x * w1.x + xa.y * w1.y + xa.z * w1.z + xa.w * w1.w +
                 xb.x * w1b.x + xb.y * w1b.y + xb.z * w1b.z + xb.w * w1b.w;
      a0[i] = fmaf(ck, d0, a0[i]);
      a1[i] = fmaf(ck, d1, a1[i]);
    }
  }
#pragma unroll
  for (int i = 0; i < 4; ++i) {
    const int b = bqg * 4 + i;
    atomicAdd(&svred[b * SREDP + ug * 2], a0[i]);      // sfinal view, pitch 18
    atomicAdd(&svred[b * SREDP + ug * 2 + 1], a1[i]);
  }
  __syncthreads();
#pragma unroll
  for (int rep = 0; rep < 2; ++rep) {
    const int idx = rep * 256 + tid;
    const int b = idx >> 4;
    const int u = idx & 15;
    partial[(size_t)kc * (NB * NU) + (size_t)(b0 + b) * NU + u] =
        svred[b * SREDP + u];
  }
}

__global__ __launch_bounds__(256, 2) void caps_fused(
    const float* __restrict__ x, const float* __restrict__ WT,
    float* __restrict__ bl, float* __restrict__ partial,
    float* __restrict__ out) {
  __shared__ float sx[KT2 * XPITCH];       // 38.6 KB  [k][b-swizzled]
  __shared__ float sw[KT2 * WKP2];         // 20.2 KB
  __shared__ float svred[BT2 * SREDP];     // 2.3 KB (sv / sfinal union)
  __shared__ float sc[KT2];
  cg::grid_group grid = cg::this_grid();
  const int tid = threadIdx.x;
  const int kc = blockIdx.x & (KC2 - 1);
  const int bgi = blockIdx.x >> 5;
  const int b0 = bgi * BT2;
  const int k0 = kc * KT2;

  {  // stage x ONCE: 32 b-rows x 72 float4, coalesced
    const float4* gx = (const float4*)(x + (size_t)b0 * (NK * ND) + k0 * ND);
    for (int i = tid; i < BT2 * 72; i += 256) {
      const int b = i / 72;
      const int q = i - b * 72;
      const float4 vx = gx[(size_t)b * (NK * ND / 4) + q];
      const int k = q >> 1, h = q & 1;
      *(float4*)&sx[k * XPITCH + b * 8 + ((b >> 3) << 2) + h * 4] = vx;
    }
  }
  if (bgi == 0)  // zero this kc-chunk's logit rows (one block per kc)
    for (int i = tid; i < KT2 * NJ; i += 256) bl[(size_t)k0 * NJ + i] = 0.f;
  stage_w(sw, WT, 0, k0, tid);
  grid.sync();

  for (int j = 0; j < NJ; ++j) {
    if (j > 0) {
      // fold prev capsule's 3rd agree update (uses W[j-1] still in LDS);
      // also emits out[:, j-1, :] (final v of capsule j-1) from kc==0 blocks.
      phaseA(sx, sw, svred, partial, bl, out, b0, k0, j - 1, (kc == 0) ? 1 : 0,
             1, tid);
      grid.sync();
      stage_w(sw, WT, j, k0, tid);  // safe: grid.sync passed; synced before use
    }
    for (int t = 0; t < 3; ++t) {
      if (t > 0) {
        phaseA(sx, sw, svred, partial, bl, out, b0, k0, j, 0, 1, tid);
        grid.sync();
      }
      for (int i = tid; i < BT2 * SREDP; i += 256) svred[i] = 0.f;
      if (tid < KT2) {  // per-k softmax of bl row, column j
        const float* row = bl + (size_t)(k0 + tid) * NJ;
        float r[NJ];
#pragma unroll
        for (int jj = 0; jj < NJ; ++jj) r[jj] = row[jj];
        float mx = r[0];
#pragma unroll
        for (int jj = 1; jj < NJ; ++jj) mx = fmaxf(mx, r[jj]);
        float se = 0.f;
#pragma unroll
        for (int jj = 0; jj < NJ; ++jj) se += __expf(r[jj] - mx);
        sc[tid] = __expf(r[j] - mx) / se;
      }
      __syncthreads();
      phaseB(sx, sw, sc, svred, partial, b0, kc, tid);
      grid.sync();
    }
  }
  // final v of capsule 9 -> out[:, 9, :]
  phaseA(sx, sw, svred, partial, bl, out, b0, k0, NJ - 1, (kc == 0) ? 1 : 0, 0,
         tid);
}

// ===========================================================================
//                      R4 FALLBACK KERNELS (verified)
// ===========================================================================
__global__ __launch_bounds__(256) void caps_part(const float* __restrict__ x,
                                                 const float* __restrict__ WT,
                                                 const float* __restrict__ cg_,
                                                 float* __restrict__ partial,
                                                 int js) {
  __shared__ float sx[16 * XP];
  __shared__ float sw[64 * WKP];
  __shared__ float sc[64];
  __shared__ float sred[4 * 16 * NU];
  const int tid = threadIdx.x;
  const int kc = blockIdx.x % KC;
  const int bgi = blockIdx.x / KC;
  const int b0 = bgi * 16;
  const int k0 = kc * 64;
  {
    const float4* gx = (const float4*)(x + (size_t)b0 * (NK * ND) + k0 * ND);
    for (int i = tid; i < 16 * 128; i += 256) {
      int b = i >> 7, q = i & 127;
      float4 vx = gx[(size_t)b * 2304 + q];
      *(float4*)&sx[b * XP + q * 4] = vx;
    }
  }
  {
    const float4* gw = (const float4*)(WT + ((size_t)js * NK + k0) * (NU * ND));
    for (int i = tid; i < 64 * 32; i += 256) {
      int k = i >> 5, r = i & 31;
      int u = r >> 1, h = r & 1;
      float4 vw = gw[i];
      *(float4*)&sw[k * WKP + (u >> 1) * 20 + (u & 1) * 8 + h * 4] = vw;
    }
  }
  if (tid < 16) *(float4*)&sc[tid * 4] = *(const float4*)(cg_ + k0 + tid * 4);
  __syncthreads();
  const int w = tid >> 6;
  const int lane = tid & 63;
  const int bpg = lane & 7;
  const int ug = lane >> 3;
  const int bb = bpg * 2;
  float a00 = 0.f, a01 = 0.f, a10 = 0.f, a11 = 0.f;
  const float* swp = sw + ug * 20;
#pragma unroll 4
  for (int kk = 0; kk < 16; ++kk) {
    const int kl = w * 16 + kk;
    const float ck = sc[kl];
    const float* xr0 = sx + bb * XP + kl * 8;
    const float4 x0 = *(const float4*)xr0;
    const float4 x0b = *(const float4*)(xr0 + 4);
    const float4 x1 = *(const float4*)(xr0 + XP);
    const float4 x1b = *(const float4*)(xr0 + XP + 4);
    const float* wr = swp + kl * WKP;
    const float4 w0 = *(const float4*)wr;
    const float4 w0b = *(const float4*)(wr + 4);
    const float4 w1 = *(const float4*)(wr + 8);
    const float4 w1b = *(const float4*)(wr + 12);
    float d00 = x0.x * w0.x + x0.y * w0.y + x0.z * w0.z + x0.w * w0.w +
                x0b.x * w0b.x + x0b.y * w0b.y + x0b.z * w0b.z + x0b.w * w0b.w;
    float d01 = x0.x * w1.x + x0.y * w1.y + x0.z * w1.z + x0.w * w1.w +
                x0b.x * w1b.x + x0b.y * w1b.y + x0b.z * w1b.z + x0b.w * w1b.w;
    float d10 = x1.x * w0.x + x1.y * w0.y + x1.z * w0.z + x1.w * w0.w +
                x1b.x * w0b.x + x1b.y * w0b.y + x1b.z * w0b.z + x1b.w * w0b.w;
    float d11 = x1.x * w1.x + x1.y * w1.y + x1.z * w1.z + x1.w * w1.w +
                x1b.x * w1b.x + x1b.y * w1b.y + x1b.z * w1b.z + x1b.w * w1b.w;
    a00 = fmaf(ck, d00, a00);
    a01 = fmaf(ck, d01, a01);
    a10 = fmaf(ck, d10, a10);
    a11 = fmaf(ck, d11, a11);
  }
  {
    float2 r0 = {a00, a01}, r1 = {a10, a11};
    *(float2*)&sred[(w * 16 + bb) * NU + ug * 2] = r0;
    *(float2*)&sred[(w * 16 + bb + 1) * NU + ug * 2] = r1;
  }
  __syncthreads();
  {
    int b = tid >> 4, u = tid & 15;
    float s = sred[(0 * 16 + b) * NU + u] + sred[(1 * 16 + b) * NU + u] +
              sred[(2 * 16 + b) * NU + u] + sred[(3 * 16 + b) * NU + u];
    partial[(size_t)kc * (NB * NU) + (size_t)(b0 + b) * NU + u] = s;
  }
}

__global__ __launch_bounds__(256) void caps_agp(const float* __restrict__ x,
                                                const float* __restrict__ WT,
                                                const float* __restrict__ partial,
                                                float* __restrict__ agp,
                                                float* __restrict__ out,
                                                int ja, int wout) {
  __shared__ float sxA[64 * XAP];
  __shared__ float sw[64 * WKP];
  __shared__ float sv[16 * NU];
  const int tid = threadIdx.x;
  const int kc = blockIdx.x % KC;
  const int bgi = blockIdx.x / KC;
  const int b0 = bgi * 16;
  const int k0 = kc * 64;
  {
    const float4* gx = (const float4*)(x + (size_t)b0 * (NK * ND) + k0 * ND);
    for (int i = tid; i < 16 * 128; i += 256) {
      int b = i >> 7, q = i & 127;
      float4 vx = gx[(size_t)b * 2304 + q];
      *(float4*)&sxA[(q >> 1) * XAP + b * 8 + (q & 1) * 4] = vx;
    }
  }
  {
    const float4* gw = (const float4*)(WT + ((size_t)ja * NK + k0) * (NU * ND));
    for (int i = tid; i < 64 * 32; i += 256) {
      int k = i >> 5, r = i & 31;
      int u = r >> 1, h = r & 1;
      float4 vw = gw[i];
      *(float4*)&sw[k * WKP + (u >> 1) * 20 + (u & 1) * 8 + h * 4] = vw;
    }
  }
  {
    int b = tid >> 4, u = tid & 15;
    const float* pp = partial + (size_t)(b0 + b) * NU + u;
    float s = 0.f;
#pragma unroll
    for (int c = 0; c < KC; ++c) s += pp[(size_t)c * (NB * NU)];
    float sq = s * s;
    sq += __shfl_xor(sq, 1, 64);
    sq += __shfl_xor(sq, 2, 64);
    sq += __shfl_xor(sq, 4, 64);
    sq += __shfl_xor(sq, 8, 64);
    const float scale = (sq / (1.f + sq)) / (sqrtf(sq) + EPSQ);
    const float vv = scale * s;
    sv[b * NU + u] = vv;
    if (wout && kc == 0) out[((size_t)(b0 + b) * NJ + ja) * NU + u] = vv;
  }
  __syncthreads();
  const int w = tid >> 6;
  const int lane = tid & 63;
  const int kl = lane & 15;
  const int ugA = lane >> 4;
  const int kloc = w * 16 + kl;
  const float* wrb = sw + kloc * WKP + (2 * ugA) * 20;
  const float4 wm0a = *(const float4*)(wrb + 0), wm0b = *(const float4*)(wrb + 4);
  const float4 wm1a = *(const float4*)(wrb + 8), wm1b = *(const float4*)(wrb + 12);
  const float4 wm2a = *(const float4*)(wrb + 20), wm2b = *(const float4*)(wrb + 24);
  const float4 wm3a = *(const float4*)(wrb + 28), wm3b = *(const float4*)(wrb + 32);
  float agc = 0.f;
#pragma unroll 4
  for (int b = 0; b < 16; ++b) {
    const float* xr = sxA + kloc * XAP + b * 8;
    const float4 xa = *(const float4*)xr;
    const float4 xb = *(const float4*)(xr + 4);
    const float4 vf = *(const float4*)(sv + b * NU + ugA * 4);
    float d0 = xa.x * wm0a.x + xa.y * wm0a.y + xa.z * wm0a.z + xa.w * wm0a.w +
               xb.x * wm0b.x + xb.y * wm0b.y + xb.z * wm0b.z + xb.w * wm0b.w;
    float d1 = xa.x * wm1a.x + xa.y * wm1a.y + xa.z * wm1a.z + xa.w * wm1a.w +
               xb.x * wm1b.x + xb.y * wm1b.y + xb.z * wm1b.z + xb.w * wm1b.w;
    float d2 = xa.x * wm2a.x + xa.y * wm2a.y + xa.z * wm2a.z + xa.w * wm2a.w +
               xb.x * wm2b.x + xb.y * wm2b.y + xb.z * wm2b.z + xb.w * wm2b.w;
    float d3 = xa.x * wm3a.x + xa.y * wm3a.y + xa.z * wm3a.z + xa.w * wm3a.w +
               xb.x * wm3b.x + xb.y * wm3b.y + xb.z * wm3b.z + xb.w * wm3b.w;
    agc = fmaf(vf.x, d0, agc);
    agc = fmaf(vf.y, d1, agc);
    agc = fmaf(vf.z, d2, agc);
    agc = fmaf(vf.w, d3, agc);
  }
  agc += __shfl_xor(agc, 16, 64);
  agc += __shfl_xor(agc, 32, 64);
  if (ugA == 0) agp[(size_t)(k0 + kloc) * BGN + bgi] = agc;
}

__global__ __launch_bounds__(256) void caps_soft(const float* __restrict__ agp,
                                                 float* __restrict__ bl,
                                                 float* __restrict__ cg_,
                                                 int ja, int jc) {
  int k = blockIdx.x * 256 + threadIdx.x;
  if (k >= NK) return;
  float* row = bl + (size_t)k * NJ;
  if (ja >= 0) {
    const float4* ap = (const float4*)(agp + (size_t)k * BGN);
    float ag = 0.f;
#pragma unroll
    for (int i = 0; i < BGN / 4; ++i) {
      float4 t4 = ap[i];
      ag += t4.x + t4.y + t4.z + t4.w;
    }
    row[ja] += ag;
  }
  float r[NJ];
#pragma unroll
  for (int jj = 0; jj < NJ; ++jj) r[jj] = row[jj];
  float mx = r[0];
#pragma unroll
  for (int jj = 1; jj < NJ; ++jj) mx = fmaxf(mx, r[jj]);
  float se = 0.f;
#pragma unroll
  for (int jj = 0; jj < NJ; ++jj) se += __expf(r[jj] - mx);
  cg_[k] = __expf(r[jc] - mx) / se;
}

__global__ __launch_bounds__(256) void caps_finout(const float* __restrict__ partial,
                                                   float* __restrict__ out) {
  int g = blockIdx.x * 256 + threadIdx.x;
  int b = g >> 4, u = g & 15;
  float s = 0.f;
#pragma unroll
  for (int c = 0; c < KC; ++c)
    s += partial[(size_t)c * (NB * NU) + (size_t)b * NU + u];
  float sq = s * s;
  sq += __shfl_xor(sq, 1, 64);
  sq += __shfl_xor(sq, 2, 64);
  sq += __shfl_xor(sq, 4, 64);
  sq += __shfl_xor(sq, 8, 64);
  const float scale = (sq / (1.f + sq)) / (sqrtf(sq) + EPSQ);
  out[((size_t)b * NJ + (NJ - 1)) * NU + u] = scale * s;
}

// ---------------------------------------------------------------------------
extern "C" void kernel_launch(void* const* d_in, const int* in_sizes, int n_in,
                              void* d_out, int out_size, void* d_ws,
                              size_t ws_size, hipStream_t stream) {
  (void)in_sizes; (void)n_in; (void)out_size; (void)ws_size;
  const float* x = (const float*)d_in[0];   // [512][1152][8][1] fp32
  const float* W = (const float*)d_in[1];   // [10][1152][8][16] fp32
  float* out = (float*)d_out;               // [512][10][16][1] fp32
  float* ws = (float*)d_ws;
  float* bl  = ws + OFF_BL;
  float* p2  = ws + OFF_P2;
  float* cgp = ws + OFF_C;
  float* agp = ws + OFF_AGP;
  float* p1  = ws + OFF_P1;
  float* WT  = ws + OFF_WT;

  caps_init<<<(WT_FLOATS + 255) / 256, 256, 0, stream>>>(W, bl, WT);

  void* args[] = {(void*)&x, (void*)&WT, (void*)&bl, (void*)&p2, (void*)&out};
  hipError_t err = hipLaunchCooperativeKernel(
      (const void*)caps_fused, dim3(KC2 * BGN2), dim3(256), args, 0, stream);
  if (err != hipSuccess) {
    (void)hipGetLastError();  // clear; use verified R4 multi-kernel path
    for (int j = 0; j < NJ; ++j) {
      for (int t = 0; t < 3; ++t) {
        const int ja = (t == 0) ? (j - 1) : j;
        if (!(j == 0 && t == 0))
          caps_agp<<<KC * BGN, 256, 0, stream>>>(x, WT, p1, agp, out, ja,
                                                 (t == 0) ? 1 : 0);
        caps_soft<<<(NK + 255) / 256, 256, 0, stream>>>(
            agp, bl, cgp, (j == 0 && t == 0) ? -1 : ja, j);
        caps_part<<<KC * BGN, 256, 0, stream>>>(x, WT, cgp, p1, j);
      }
    }
    caps_finout<<<(NB * NU) / 256, 256, 0, stream>>>(p1, out);
  }
}

// Round 6
// 708.660 us; speedup vs baseline: 5.5293x; 5.5293x over previous
//
#include <hip/hip_runtime.h>

#define NB 512      // batch
#define NK 1152     // input capsules
#define ND 8        // in dim
#define NU 16       // out dim
#define NJ 10       // output capsules
#define EPSQ 1e-7f

#define KT 32       // k per tile
#define KCN 36      // k chunks (KT*KCN == NK)
#define BT 16       // b per tile
#define BGN 32      // b groups (BT*BGN == NB)
#define XPB 260     // part: x pitch per b (32k*8 + 4) -> 2-way banks max
#define XPK 132     // agp: x pitch per k (16b*8 + 4) -> 2-way banks max
#define WKP 140     // w pitch per k, u-pair swizzle -> conflict-free reads
// pair p=(u>>1) base = 16p + 4*(p>>1); odd u at +8
#define WOFF(u) ((((u) >> 1) << 4) + (((u) >> 2) << 2) + (((u) & 1) << 3))

// ws layout (floats); harness ws (~268 MB) >> 7.1 MB needed
#define OFF_BL 0                       // b_logits [NK][NJ]        11520
#define OFF_P  11520                   // partial [KCN][NB][NU]    294912
#define OFF_WT (OFF_P + KCN*NB*NU)     // WT [NJ][NK][NU][ND]
#define WT_FLOATS (NJ*NK*NU*ND)        // 1474560

// ---------------------------------------------------------------------------
// init: zero b_logits, build WT[j][k][u][d] = W[j][k][d][u]
// ---------------------------------------------------------------------------
__global__ __launch_bounds__(256) void caps_init(const float* __restrict__ W,
                                                 float* __restrict__ bl,
                                                 float* __restrict__ WT) {
  int idx = blockIdx.x * 256 + threadIdx.x;
  if (idx < NK * NJ) bl[idx] = 0.f;
  if (idx < WT_FLOATS) {
    int d = idx & 7;
    int u = (idx >> 3) & 15;
    int k = (idx >> 7) % NK;
    int j = idx / (NK * NU * ND);
    WT[idx] = W[((size_t)(j * NK + k) * ND + d) * NU + u];
  }
}

// ---------------------------------------------------------------------------
// caps_part: block (kc,bgi) = 16 b x 32 k tile.
// Reads bl rows -> softmax col js in-block (replaces caps_soft), then
// partial[kc][b][u] = sum_{k in tile} c_k * (x[b,k,:]·W[js,k,:,u]).
// Wave w owns k = w*8..w*8+7; lane = (ug=lane>>3 u-pair, bpg=lane&7 b-pair).
// ---------------------------------------------------------------------------
__global__ __launch_bounds__(256) void caps_part(const float* __restrict__ x,
                                                 const float* __restrict__ WT,
                                                 const float* __restrict__ bl,
                                                 float* __restrict__ partial,
                                                 int js) {
  __shared__ float sx[BT * XPB];       // 16.6 KB [b][k*8+d]
  __shared__ float sw[KT * WKP];       // 17.9 KB [k][u-swizzled]
  __shared__ float sc[KT];
  __shared__ float sred[4 * BT * NU];  // 4 KB [wave][b][u]
  const int tid = threadIdx.x;
  const int kc = blockIdx.x % KCN;
  const int bgi = blockIdx.x / KCN;
  const int b0 = bgi * BT;
  const int k0 = kc * KT;

  {  // stage x: 16 b-rows x 64 float4 (coalesced)
    const float4* gx = (const float4*)(x + (size_t)b0 * (NK * ND) + k0 * ND);
    for (int i = tid; i < BT * 64; i += 256) {
      const int b = i >> 6, q = i & 63;
      const float4 vx = gx[(size_t)b * (NK * ND / 4) + q];
      *(float4*)&sx[b * XPB + q * 4] = vx;
    }
  }
  {  // stage w: 32 k-rows x 32 float4 (contiguous in WT)
    const float4* gw = (const float4*)(WT + ((size_t)js * NK + k0) * (NU * ND));
    for (int i = tid; i < KT * 32; i += 256) {
      const int k = i >> 5, r = i & 31;
      const int u = r >> 1, h = r & 1;
      const float4 vw = gw[i];
      *(float4*)&sw[k * WKP + WOFF(u) + h * 4] = vw;
    }
  }
  if (tid < KT) {  // softmax of bl row (k0+tid), column js
    const float* row = bl + (size_t)(k0 + tid) * NJ;
    float r[NJ];
#pragma unroll
    for (int jj = 0; jj < NJ; ++jj) r[jj] = row[jj];
    float mx = r[0];
#pragma unroll
    for (int jj = 1; jj < NJ; ++jj) mx = fmaxf(mx, r[jj]);
    float se = 0.f;
#pragma unroll
    for (int jj = 0; jj < NJ; ++jj) se += __expf(r[jj] - mx);
    sc[tid] = __expf(r[js] - mx) / se;
  }
  __syncthreads();

  const int w = tid >> 6;
  const int lane = tid & 63;
  const int bpg = lane & 7;
  const int ug = lane >> 3;
  const int bb = bpg * 2;
  float a00 = 0.f, a01 = 0.f, a10 = 0.f, a11 = 0.f;
  const float* swp = sw + WOFF(2 * ug);  // = 16*ug + 4*(ug>>1)
#pragma unroll
  for (int kk = 0; kk < 8; ++kk) {
    const int kl = w * 8 + kk;
    const float ck = sc[kl];
    const float* xr0 = sx + bb * XPB + kl * 8;
    const float4 x0 = *(const float4*)xr0;
    const float4 x0b = *(const float4*)(xr0 + 4);
    const float4 x1 = *(const float4*)(xr0 + XPB);
    const float4 x1b = *(const float4*)(xr0 + XPB + 4);
    const float* wr = swp + kl * WKP;
    const float4 w0 = *(const float4*)wr;
    const float4 w0b = *(const float4*)(wr + 4);
    const float4 w1 = *(const float4*)(wr + 8);
    const float4 w1b = *(const float4*)(wr + 12);
    float d00 = x0.x * w0.x + x0.y * w0.y + x0.z * w0.z + x0.w * w0.w +
                x0b.x * w0b.x + x0b.y * w0b.y + x0b.z * w0b.z + x0b.w * w0b.w;
    float d01 = x0.x * w1.x + x0.y * w1.y + x0.z * w1.z + x0.w * w1.w +
                x0b.x * w1b.x + x0b.y * w1b.y + x0b.z * w1b.z + x0b.w * w1b.w;
    float d10 = x1.x * w0.x + x1.y * w0.y + x1.z * w0.z + x1.w * w0.w +
                x1b.x * w0b.x + x1b.y * w0b.y + x1b.z * w0b.z + x1b.w * w0b.w;
    float d11 = x1.x * w1.x + x1.y * w1.y + x1.z * w1.z + x1.w * w1.w +
                x1b.x * w1b.x + x1b.y * w1b.y + x1b.z * w1b.z + x1b.w * w1b.w;
    a00 = fmaf(ck, d00, a00);
    a01 = fmaf(ck, d01, a01);
    a10 = fmaf(ck, d10, a10);
    a11 = fmaf(ck, d11, a11);
  }
  {  // per-wave 16b x 16u tile -> LDS (same pattern as R4: measured 0 conflicts)
    float2 r0 = {a00, a01}, r1 = {a10, a11};
    *(float2*)&sred[(w * BT + bb) * NU + ug * 2] = r0;
    *(float2*)&sred[(w * BT + bb + 1) * NU + ug * 2] = r1;
  }
  __syncthreads();
  {  // sum the 4 waves' k-ranges, write partial
    const int b = tid >> 4, u = tid & 15;
    const float s = sred[(0 * BT + b) * NU + u] + sred[(1 * BT + b) * NU + u] +
                    sred[(2 * BT + b) * NU + u] + sred[(3 * BT + b) * NU + u];
    partial[(size_t)kc * (NB * NU) + (size_t)(b0 + b) * NU + u] = s;
  }
}

// ---------------------------------------------------------------------------
// caps_agp: block (kc,bgi). Recomputes v = squash(sum_kc partial) for its 16 b
// (writes out[:,ja,:] from kc==0 blocks when wout), then agree for column ja:
// atomicAdd(&bl[k][ja], sum_{b,u} uhat*v) -- no agp array, no caps_soft.
// Wave-pairs: kloc = (w>>1)*16 + (lane&15); b-half = (w&1)*8; ugA = lane>>4.
// ---------------------------------------------------------------------------
__global__ __launch_bounds__(256) void caps_agp(const float* __restrict__ x,
                                                const float* __restrict__ WT,
                                                const float* __restrict__ partial,
                                                float* __restrict__ bl,
                                                float* __restrict__ out,
                                                int ja, int wout) {
  __shared__ float sxA[KT * XPK];  // 16.9 KB [k][b*8+d]
  __shared__ float sw[KT * WKP];   // 17.9 KB
  __shared__ float sv[BT * NU];    // 1 KB
  const int tid = threadIdx.x;
  const int kc = blockIdx.x % KCN;
  const int bgi = blockIdx.x / KCN;
  const int b0 = bgi * BT;
  const int k0 = kc * KT;

  {  // stage x transposed: [k][b]
    const float4* gx = (const float4*)(x + (size_t)b0 * (NK * ND) + k0 * ND);
    for (int i = tid; i < BT * 64; i += 256) {
      const int b = i >> 6, q = i & 63;
      const float4 vx = gx[(size_t)b * (NK * ND / 4) + q];
      *(float4*)&sxA[(q >> 1) * XPK + b * 8 + (q & 1) * 4] = vx;
    }
  }
  {  // stage w for column ja
    const float4* gw = (const float4*)(WT + ((size_t)ja * NK + k0) * (NU * ND));
    for (int i = tid; i < KT * 32; i += 256) {
      const int k = i >> 5, r = i & 31;
      const int u = r >> 1, h = r & 1;
      const float4 vw = gw[i];
      *(float4*)&sw[k * WKP + WOFF(u) + h * 4] = vw;
    }
  }
  {  // v = squash(sum of 36 partials); wave = 4b x 16u, u = low 4 lane bits
    const int b = tid >> 4, u = tid & 15;
    const float* pp = partial + (size_t)(b0 + b) * NU + u;
    float s = 0.f;
#pragma unroll
    for (int c = 0; c < KCN; ++c) s += pp[(size_t)c * (NB * NU)];
    float sq = s * s;
    sq += __shfl_xor(sq, 1, 64);
    sq += __shfl_xor(sq, 2, 64);
    sq += __shfl_xor(sq, 4, 64);
    sq += __shfl_xor(sq, 8, 64);
    const float scale = (sq / (1.f + sq)) / (sqrtf(sq) + EPSQ);
    const float vv = scale * s;
    sv[b * NU + u] = vv;
    if (wout && kc == 0) out[((size_t)(b0 + b) * NJ + ja) * NU + u] = vv;
  }
  __syncthreads();

  const int w = tid >> 6;
  const int lane = tid & 63;
  const int kl = lane & 15;
  const int ugA = lane >> 4;
  const int kloc = (w >> 1) * 16 + kl;
  const int bh = (w & 1) * 8;
  // hoist w fragment: u = 4*ugA + m, m=0..3 -> 32 contiguous floats (WKP swizzle)
  const float* wrb = sw + kloc * WKP + 36 * ugA;
  const float4 wm0a = *(const float4*)(wrb + 0),  wm0b = *(const float4*)(wrb + 4);
  const float4 wm1a = *(const float4*)(wrb + 8),  wm1b = *(const float4*)(wrb + 12);
  const float4 wm2a = *(const float4*)(wrb + 16), wm2b = *(const float4*)(wrb + 20);
  const float4 wm3a = *(const float4*)(wrb + 24), wm3b = *(const float4*)(wrb + 28);
  float agc = 0.f;
#pragma unroll
  for (int i = 0; i < 8; ++i) {
    const int b = bh + i;
    const float* xr = sxA + kloc * XPK + b * 8;
    const float4 xa = *(const float4*)xr;
    const float4 xb = *(const float4*)(xr + 4);
    const float4 vf = *(const float4*)(sv + b * NU + ugA * 4);
    float d0 = xa.x * wm0a.x + xa.y * wm0a.y + xa.z * wm0a.z + xa.w * wm0a.w +
               xb.x * wm0b.x + xb.y * wm0b.y + xb.z * wm0b.z + xb.w * wm0b.w;
    float d1 = xa.x * wm1a.x + xa.y * wm1a.y + xa.z * wm1a.z + xa.w * wm1a.w +
               xb.x * wm1b.x + xb.y * wm1b.y + xb.z * wm1b.z + xb.w * wm1b.w;
    float d2 = xa.x * wm2a.x + xa.y * wm2a.y + xa.z * wm2a.z + xa.w * wm2a.w +
               xb.x * wm2b.x + xb.y * wm2b.y + xb.z * wm2b.z + xb.w * wm2b.w;
    float d3 = xa.x * wm3a.x + xa.y * wm3a.y + xa.z * wm3a.z + xa.w * wm3a.w +
               xb.x * wm3b.x + xb.y * wm3b.y + xb.z * wm3b.z + xb.w * wm3b.w;
    agc = fmaf(vf.x, d0, agc);
    agc = fmaf(vf.y, d1, agc);
    agc = fmaf(vf.z, d2, agc);
    agc = fmaf(vf.w, d3, agc);
  }
  agc += __shfl_xor(agc, 16, 64);  // reduce over ugA
  agc += __shfl_xor(agc, 32, 64);
  if (ugA == 0)  // 2 atomics per k (the two b-halves); visible next kernel
    atomicAdd(&bl[(size_t)(k0 + kloc) * NJ + ja], agc);
}

// ---------------------------------------------------------------------------
// caps_finout: final v for capsule 9 -> out[:, 9, :]
// ---------------------------------------------------------------------------
__global__ __launch_bounds__(256) void caps_finout(const float* __restrict__ partial,
                                                   float* __restrict__ out) {
  const int g = blockIdx.x * 256 + threadIdx.x;  // 8192
  const int b = g >> 4, u = g & 15;
  float s = 0.f;
#pragma unroll
  for (int c = 0; c < KCN; ++c)
    s += partial[(size_t)c * (NB * NU) + (size_t)b * NU + u];
  float sq = s * s;
  sq += __shfl_xor(sq, 1, 64);
  sq += __shfl_xor(sq, 2, 64);
  sq += __shfl_xor(sq, 4, 64);
  sq += __shfl_xor(sq, 8, 64);
  const float scale = (sq / (1.f + sq)) / (sqrtf(sq) + EPSQ);
  out[((size_t)b * NJ + (NJ - 1)) * NU + u] = scale * s;
}

// ---------------------------------------------------------------------------
extern "C" void kernel_launch(void* const* d_in, const int* in_sizes, int n_in,
                              void* d_out, int out_size, void* d_ws,
                              size_t ws_size, hipStream_t stream) {
  (void)in_sizes; (void)n_in; (void)out_size; (void)ws_size;
  const float* x = (const float*)d_in[0];   // [512][1152][8][1] fp32
  const float* W = (const float*)d_in[1];   // [10][1152][8][16] fp32
  float* out = (float*)d_out;               // [512][10][16][1] fp32
  float* ws = (float*)d_ws;
  float* bl = ws + OFF_BL;
  float* pt = ws + OFF_P;
  float* WT = ws + OFF_WT;

  caps_init<<<(WT_FLOATS + 255) / 256, 256, 0, stream>>>(W, bl, WT);
  for (int n = 0; n < NJ * 3; ++n) {
    const int j = n / 3, t = n - 3 * j;
    if (n > 0) {
      // agree for iteration n-1: capsule ja = (t==0 ? j-1 : j); t==0 also
      // emits the final v of capsule j-1 to out (kc==0 blocks).
      const int ja = (t == 0) ? (j - 1) : j;
      caps_agp<<<KCN * BGN, 256, 0, stream>>>(x, WT, pt, bl, out, ja,
                                              (t == 0) ? 1 : 0);
    }
    caps_part<<<KCN * BGN, 256, 0, stream>>>(x, WT, bl, pt, j);
  }
  caps_finout<<<(NB * NU) / 256, 256, 0, stream>>>(pt, out);
}

// Round 7
// 699.641 us; speedup vs baseline: 5.6006x; 1.0129x over previous
//
#include <hip/hip_runtime.h>

#define NB 512      // batch
#define NK 1152     // input capsules
#define ND 8        // in dim
#define NU 16       // out dim
#define NJ 10       // output capsules
#define EPSQ 1e-7f

#define KT 32       // k per tile
#define KCN 36      // k chunks (KT*KCN == NK)
#define BT 16       // b per tile
#define BGN 32      // b groups (BT*BGN == NB)
#define XPB 260     // part: x pitch per b (32k*8 + 4)
#define XPK 132     // agp: x pitch per k (16b*8 + 4)
#define WKP 140     // w pitch per k, u-pair swizzle
#define SREDP 20    // part cross-wave reduce pitch (f4-aligned, bank-spread)
// pair p=(u>>1) base = 16p + 4*(p>>1); odd u at +8  ->  u=4a+m lives at 36a+8m
#define WOFF(u) ((((u) >> 1) << 4) + (((u) >> 2) << 2) + (((u) & 1) << 3))

// ws layout (floats); harness ws (~268 MB) >> 7.1 MB needed
#define OFF_BL 0                       // b_logits [NK][NJ]        11520
#define OFF_P  11520                   // partial [KCN][NB][NU]    294912
#define OFF_WT (OFF_P + KCN*NB*NU)     // WT [NJ][NK][NU][ND]
#define WT_FLOATS (NJ*NK*NU*ND)        // 1474560

// ---------------------------------------------------------------------------
// init: zero b_logits, build WT[j][k][u][d] = W[j][k][d][u]
// ---------------------------------------------------------------------------
__global__ __launch_bounds__(256) void caps_init(const float* __restrict__ W,
                                                 float* __restrict__ bl,
                                                 float* __restrict__ WT) {
  int idx = blockIdx.x * 256 + threadIdx.x;
  if (idx < NK * NJ) bl[idx] = 0.f;
  if (idx < WT_FLOATS) {
    int d = idx & 7;
    int u = (idx >> 3) & 15;
    int k = (idx >> 7) % NK;
    int j = idx / (NK * NU * ND);
    WT[idx] = W[((size_t)(j * NK + k) * ND + d) * NU + u];
  }
}

// ---------------------------------------------------------------------------
// caps_part: block (kc,bgi) = 16 b x 32 k tile. Softmax col js in-block, then
// partial[kc][b][u] = sum_{k in tile} c_k * (x[b,k,:]·W[js,k,:,u]).
// Wave w owns k = w*8..+7. Lane = (kq=lane>>4: 2 k's, bq: 4 b's, uq: 4 u's)
// -> 4b x 4u micro-tile, 9 FMA per ds_read_b128 (R6 was 4.5).
// ---------------------------------------------------------------------------
__global__ __launch_bounds__(256, 4) void caps_part(
    const float* __restrict__ x, const float* __restrict__ WT,
    const float* __restrict__ bl, float* __restrict__ partial, int js) {
  __shared__ float sx[BT * XPB];        // 16.6 KB [b][k*8+d]
  __shared__ float sw[KT * WKP];        // 17.9 KB [k][u-swizzled]
  __shared__ float sc[KT];
  __shared__ float sred[4 * BT * SREDP];  // 5.1 KB [wave][b][u padded]
  const int tid = threadIdx.x;
  const int kc = blockIdx.x % KCN;
  const int bgi = blockIdx.x / KCN;
  const int b0 = bgi * BT;
  const int k0 = kc * KT;

  {  // stage x: 16 b-rows x 64 float4 (coalesced)
    const float4* gx = (const float4*)(x + (size_t)b0 * (NK * ND) + k0 * ND);
    for (int i = tid; i < BT * 64; i += 256) {
      const int b = i >> 6, q = i & 63;
      const float4 vx = gx[(size_t)b * (NK * ND / 4) + q];
      *(float4*)&sx[b * XPB + q * 4] = vx;
    }
  }
  {  // stage w: 32 k-rows x 32 float4 (contiguous in WT)
    const float4* gw = (const float4*)(WT + ((size_t)js * NK + k0) * (NU * ND));
    for (int i = tid; i < KT * 32; i += 256) {
      const int k = i >> 5, r = i & 31;
      const int u = r >> 1, h = r & 1;
      const float4 vw = gw[i];
      *(float4*)&sw[k * WKP + WOFF(u) + h * 4] = vw;
    }
  }
  if (tid < KT) {  // softmax of bl row (k0+tid), column js
    const float* row = bl + (size_t)(k0 + tid) * NJ;
    float r[NJ];
#pragma unroll
    for (int jj = 0; jj < NJ; ++jj) r[jj] = row[jj];
    float mx = r[0];
#pragma unroll
    for (int jj = 1; jj < NJ; ++jj) mx = fmaxf(mx, r[jj]);
    float se = 0.f;
#pragma unroll
    for (int jj = 0; jj < NJ; ++jj) se += __expf(r[jj] - mx);
    sc[tid] = __expf(r[js] - mx) / se;
  }
  __syncthreads();

  const int w = tid >> 6;
  const int lane = tid & 63;
  const int kq = lane >> 4;
  const int bq = (lane >> 2) & 3;
  const int uq = lane & 3;
  float a[4][4];
#pragma unroll
  for (int i = 0; i < 4; ++i)
#pragma unroll
    for (int m = 0; m < 4; ++m) a[i][m] = 0.f;

#pragma unroll
  for (int kk = 0; kk < 2; ++kk) {
    const int kl = w * 8 + kq * 2 + kk;
    const float ck = sc[kl];
    float4 xa[4], xb[4];
#pragma unroll
    for (int i = 0; i < 4; ++i) {
      const float* xr = sx + (bq * 4 + i) * XPB + kl * 8;
      xa[i] = *(const float4*)xr;
      xb[i] = *(const float4*)(xr + 4);
    }
    float4 wa[4], wb[4];
    const float* wr = sw + kl * WKP + 36 * uq;  // 4 u's at +0,+8,+16,+24
#pragma unroll
    for (int m = 0; m < 4; ++m) {
      wa[m] = *(const float4*)(wr + 8 * m);
      wb[m] = *(const float4*)(wr + 8 * m + 4);
    }
#pragma unroll
    for (int i = 0; i < 4; ++i)
#pragma unroll
      for (int m = 0; m < 4; ++m) {
        const float dot =
            xa[i].x * wa[m].x + xa[i].y * wa[m].y + xa[i].z * wa[m].z +
            xa[i].w * wa[m].w + xb[i].x * wb[m].x + xb[i].y * wb[m].y +
            xb[i].z * wb[m].z + xb[i].w * wb[m].w;
        a[i][m] = fmaf(ck, dot, a[i][m]);
      }
  }
  // reduce over kq (lane bits 4,5): butterfly on all 16 accumulators
#pragma unroll
  for (int i = 0; i < 4; ++i)
#pragma unroll
    for (int m = 0; m < 4; ++m) {
      a[i][m] += __shfl_xor(a[i][m], 16, 64);
      a[i][m] += __shfl_xor(a[i][m], 32, 64);
    }
  if (kq == 0) {  // 16 lanes (bq,uq) hold the wave's 16b x 16u tile
#pragma unroll
    for (int i = 0; i < 4; ++i) {
      const float4 t4 = {a[i][0], a[i][1], a[i][2], a[i][3]};
      *(float4*)&sred[(w * BT + bq * 4 + i) * SREDP + uq * 4] = t4;
    }
  }
  __syncthreads();
  {  // sum the 4 waves' k-ranges, write partial
    const int b = tid >> 4, u = tid & 15;
    const float s =
        sred[(0 * BT + b) * SREDP + u] + sred[(1 * BT + b) * SREDP + u] +
        sred[(2 * BT + b) * SREDP + u] + sred[(3 * BT + b) * SREDP + u];
    partial[(size_t)kc * (NB * NU) + (size_t)(b0 + b) * NU + u] = s;
  }
}

// ---------------------------------------------------------------------------
// caps_agp: block (kc,bgi). Recomputes v = squash(sum_kc partial) for its 16 b
// (writes out[:,ja,:] from kc==0 blocks when wout), then agree for column ja:
// atomicAdd(&bl[k][ja], sum_{b,u} uhat*v).
// Wave-pairs: kloc = (w>>1)*16 + (lane&15); b-half = (w&1)*8; ugA = lane>>4.
// ---------------------------------------------------------------------------
__global__ __launch_bounds__(256, 4) void caps_agp(
    const float* __restrict__ x, const float* __restrict__ WT,
    const float* __restrict__ partial, float* __restrict__ bl,
    float* __restrict__ out, int ja, int wout) {
  __shared__ float sxA[KT * XPK];  // 16.9 KB [k][b*8+d]
  __shared__ float sw[KT * WKP];   // 17.9 KB
  __shared__ float sv[BT * NU];    // 1 KB
  const int tid = threadIdx.x;
  const int kc = blockIdx.x % KCN;
  const int bgi = blockIdx.x / KCN;
  const int b0 = bgi * BT;
  const int k0 = kc * KT;

  {  // stage x transposed: [k][b]
    const float4* gx = (const float4*)(x + (size_t)b0 * (NK * ND) + k0 * ND);
    for (int i = tid; i < BT * 64; i += 256) {
      const int b = i >> 6, q = i & 63;
      const float4 vx = gx[(size_t)b * (NK * ND / 4) + q];
      *(float4*)&sxA[(q >> 1) * XPK + b * 8 + (q & 1) * 4] = vx;
    }
  }
  {  // stage w for column ja
    const float4* gw = (const float4*)(WT + ((size_t)ja * NK + k0) * (NU * ND));
    for (int i = tid; i < KT * 32; i += 256) {
      const int k = i >> 5, r = i & 31;
      const int u = r >> 1, h = r & 1;
      const float4 vw = gw[i];
      *(float4*)&sw[k * WKP + WOFF(u) + h * 4] = vw;
    }
  }
  {  // v = squash(sum of 36 partials); wave = 4b x 16u, u = low 4 lane bits
    const int b = tid >> 4, u = tid & 15;
    const float* pp = partial + (size_t)(b0 + b) * NU + u;
    float s = 0.f;
#pragma unroll
    for (int c = 0; c < KCN; ++c) s += pp[(size_t)c * (NB * NU)];
    float sq = s * s;
    sq += __shfl_xor(sq, 1, 64);
    sq += __shfl_xor(sq, 2, 64);
    sq += __shfl_xor(sq, 4, 64);
    sq += __shfl_xor(sq, 8, 64);
    const float scale = (sq / (1.f + sq)) / (sqrtf(sq) + EPSQ);
    const float vv = scale * s;
    sv[b * NU + u] = vv;
    if (wout && kc == 0) out[((size_t)(b0 + b) * NJ + ja) * NU + u] = vv;
  }
  __syncthreads();

  const int w = tid >> 6;
  const int lane = tid & 63;
  const int kl = lane & 15;
  const int ugA = lane >> 4;
  const int kloc = (w >> 1) * 16 + kl;
  const int bh = (w & 1) * 8;
  // hoist w fragment: u = 4*ugA + m, m=0..3 -> 32 contiguous floats (WKP swizzle)
  const float* wrb = sw + kloc * WKP + 36 * ugA;
  const float4 wm0a = *(const float4*)(wrb + 0),  wm0b = *(const float4*)(wrb + 4);
  const float4 wm1a = *(const float4*)(wrb + 8),  wm1b = *(const float4*)(wrb + 12);
  const float4 wm2a = *(const float4*)(wrb + 16), wm2b = *(const float4*)(wrb + 20);
  const float4 wm3a = *(const float4*)(wrb + 24), wm3b = *(const float4*)(wrb + 28);
  float agc = 0.f;
#pragma unroll
  for (int i = 0; i < 8; ++i) {
    const int b = bh + i;
    const float* xr = sxA + kloc * XPK + b * 8;
    const float4 xa = *(const float4*)xr;
    const float4 xb = *(const float4*)(xr + 4);
    const float4 vf = *(const float4*)(sv + b * NU + ugA * 4);
    float d0 = xa.x * wm0a.x + xa.y * wm0a.y + xa.z * wm0a.z + xa.w * wm0a.w +
               xb.x * wm0b.x + xb.y * wm0b.y + xb.z * wm0b.z + xb.w * wm0b.w;
    float d1 = xa.x * wm1a.x + xa.y * wm1a.y + xa.z * wm1a.z + xa.w * wm1a.w +
               xb.x * wm1b.x + xb.y * wm1b.y + xb.z * wm1b.z + xb.w * wm1b.w;
    float d2 = xa.x * wm2a.x + xa.y * wm2a.y + xa.z * wm2a.z + xa.w * wm2a.w +
               xb.x * wm2b.x + xb.y * wm2b.y + xb.z * wm2b.z + xb.w * wm2b.w;
    float d3 = xa.x * wm3a.x + xa.y * wm3a.y + xa.z * wm3a.z + xa.w * wm3a.w +
               xb.x * wm3b.x + xb.y * wm3b.y + xb.z * wm3b.z + xb.w * wm3b.w;
    agc = fmaf(vf.x, d0, agc);
    agc = fmaf(vf.y, d1, agc);
    agc = fmaf(vf.z, d2, agc);
    agc = fmaf(vf.w, d3, agc);
  }
  agc += __shfl_xor(agc, 16, 64);  // reduce over ugA
  agc += __shfl_xor(agc, 32, 64);
  if (ugA == 0)  // 2 atomics per k (the two b-halves); visible next kernel
    atomicAdd(&bl[(size_t)(k0 + kloc) * NJ + ja], agc);
}

// ---------------------------------------------------------------------------
// caps_finout: final v for capsule 9 -> out[:, 9, :]
// ---------------------------------------------------------------------------
__global__ __launch_bounds__(256) void caps_finout(const float* __restrict__ partial,
                                                   float* __restrict__ out) {
  const int g = blockIdx.x * 256 + threadIdx.x;  // 8192
  const int b = g >> 4, u = g & 15;
  float s = 0.f;
#pragma unroll
  for (int c = 0; c < KCN; ++c)
    s += partial[(size_t)c * (NB * NU) + (size_t)b * NU + u];
  float sq = s * s;
  sq += __shfl_xor(sq, 1, 64);
  sq += __shfl_xor(sq, 2, 64);
  sq += __shfl_xor(sq, 4, 64);
  sq += __shfl_xor(sq, 8, 64);
  const float scale = (sq / (1.f + sq)) / (sqrtf(sq) + EPSQ);
  out[((size_t)b * NJ + (NJ - 1)) * NU + u] = scale * s;
}

// ---------------------------------------------------------------------------
extern "C" void kernel_launch(void* const* d_in, const int* in_sizes, int n_in,
                              void* d_out, int out_size, void* d_ws,
                              size_t ws_size, hipStream_t stream) {
  (void)in_sizes; (void)n_in; (void)out_size; (void)ws_size;
  const float* x = (const float*)d_in[0];   // [512][1152][8][1] fp32
  const float* W = (const float*)d_in[1];   // [10][1152][8][16] fp32
  float* out = (float*)d_out;               // [512][10][16][1] fp32
  float* ws = (float*)d_ws;
  float* bl = ws + OFF_BL;
  float* pt = ws + OFF_P;
  float* WT = ws + OFF_WT;

  caps_init<<<(WT_FLOATS + 255) / 256, 256, 0, stream>>>(W, bl, WT);
  for (int n = 0; n < NJ * 3; ++n) {
    const int j = n / 3, t = n - 3 * j;
    if (n > 0) {
      // agree for iteration n-1: capsule ja = (t==0 ? j-1 : j); t==0 also
      // emits the final v of capsule j-1 to out (kc==0 blocks).
      const int ja = (t == 0) ? (j - 1) : j;
      caps_agp<<<KCN * BGN, 256, 0, stream>>>(x, WT, pt, bl, out, ja,
                                              (t == 0) ? 1 : 0);
    }
    caps_part<<<KCN * BGN, 256, 0, stream>>>(x, WT, bl, pt, j);
  }
  caps_finout<<<(NB * NU) / 256, 256, 0, stream>>>(pt, out);
}

// Round 9
// 672.742 us; speedup vs baseline: 5.8245x; 1.0400x over previous
//
#include <hip/hip_runtime.h>

#define NB 512      // batch
#define NK 1152     // input capsules
#define ND 8        // in dim
#define NU 16       // out dim
#define NJ 10       // output capsules
#define EPSQ 1e-7f

#define KT 36       // k per tile
#define KCN 32      // k chunks (KT*KCN == NK); kc = blockIdx&31 -> XCD = kc%8
#define BT 16       // b per tile
#define BGN 32      // b groups (BT*BGN == NB)
#define XPB 292     // part: x pitch per b (36k*8 + 4)
#define XPK 132     // agp: x pitch per k (16b*8 + 4)
#define WKP 140     // w pitch per k — swizzle span is 140 (max WOFF=132+8);
                    // R8's 136 truncated u=15 into the next row (absmax 0.65)
#define SREDP 20    // part cross-wave reduce pitch
#define SVP 18      // agp sv pitch (conflict-free vs 16)
// u-pair swizzle: pair p=(u>>1) base = 16p+4*(p>>1); odd u at +8.
// For u=4a+m: offset = 36a + 8m  (fragment hoist-friendly).
#define WOFF(u) ((((u) >> 1) << 4) + (((u) >> 2) << 2) + (((u) & 1) << 3))

// ws layout (floats); harness ws (~268 MB) >> 7 MB needed
#define OFF_BL 0                       // b_logits [NK][NJ]        11520
#define OFF_P  11520                   // partial [KCN][NB][NU]    262144
#define OFF_WT (OFF_P + KCN*NB*NU)     // WT [NJ][NK][NU][ND]
#define WT_FLOATS (NJ*NK*NU*ND)        // 1474560

// ---------------------------------------------------------------------------
// init: zero b_logits, build WT[j][k][u][d] = W[j][k][d][u]
// ---------------------------------------------------------------------------
__global__ __launch_bounds__(256) void caps_init(const float* __restrict__ W,
                                                 float* __restrict__ bl,
                                                 float* __restrict__ WT) {
  int idx = blockIdx.x * 256 + threadIdx.x;
  if (idx < NK * NJ) bl[idx] = 0.f;
  if (idx < WT_FLOATS) {
    int d = idx & 7;
    int u = (idx >> 3) & 15;
    int k = (idx >> 7) % NK;
    int j = idx / (NK * NU * ND);
    WT[idx] = W[((size_t)(j * NK + k) * ND + d) * NU + u];
  }
}

// ---------------------------------------------------------------------------
// caps_part: block (kc,bgi) = 16 b x 36 k tile. Softmax col js in-block, then
// partial[kc][b][u] = sum_{k in tile} c_k * (x[b,k,:]·W[js,k,:,u]).
// Wave w owns k = w*9..+8. Lane = (kq 4-way k-split, bq 4 b's, uq 4 u's);
// masked 3rd iteration covers the 9th k. sred aliases sx (dead after compute).
// ---------------------------------------------------------------------------
__global__ __launch_bounds__(256, 4) void caps_part(
    const float* __restrict__ x, const float* __restrict__ WT,
    const float* __restrict__ bl, float* __restrict__ partial, int js) {
  __shared__ float smem[BT * XPB + KT * WKP + KT];  // 38.99 KB -> 4 blocks/CU
  float* sx = smem;                // [b][k*8+d] pitch 292
  float* sw = smem + BT * XPB;     // [k][u-swizzled] pitch 140
  float* sc = smem + BT * XPB + KT * WKP;
  float* sred = smem;              // aliases sx after compute (barrier-guarded)
  const int tid = threadIdx.x;
  const int kc = blockIdx.x & (KCN - 1);   // kc%8 == blockIdx%8 == XCD slot
  const int bgi = blockIdx.x >> 5;
  const int b0 = bgi * BT;
  const int k0 = kc * KT;

  {  // stage x: 16 b-rows x 72 float4 (coalesced)
    const float4* gx = (const float4*)(x + (size_t)b0 * (NK * ND) + k0 * ND);
    for (int i = tid; i < BT * 72; i += 256) {
      const int b = i / 72, q = i - b * 72;
      const float4 vx = gx[(size_t)b * (NK * ND / 4) + q];
      *(float4*)&sx[b * XPB + q * 4] = vx;
    }
  }
  {  // stage w: 36 k-rows x 32 float4 (contiguous in WT)
    const float4* gw = (const float4*)(WT + ((size_t)js * NK + k0) * (NU * ND));
    for (int i = tid; i < KT * 32; i += 256) {
      const int k = i >> 5, r = i & 31;
      const int u = r >> 1, h = r & 1;
      const float4 vw = gw[i];
      *(float4*)&sw[k * WKP + WOFF(u) + h * 4] = vw;
    }
  }
  if (tid < KT) {  // softmax of bl row (k0+tid), column js
    const float* row = bl + (size_t)(k0 + tid) * NJ;
    float r[NJ];
#pragma unroll
    for (int jj = 0; jj < NJ; ++jj) r[jj] = row[jj];
    float mx = r[0];
#pragma unroll
    for (int jj = 1; jj < NJ; ++jj) mx = fmaxf(mx, r[jj]);
    float se = 0.f;
#pragma unroll
    for (int jj = 0; jj < NJ; ++jj) se += __expf(r[jj] - mx);
    sc[tid] = __expf(r[js] - mx) / se;
  }
  __syncthreads();

  const int w = tid >> 6;
  const int lane = tid & 63;
  const int kq = lane >> 4;
  const int bq = (lane >> 2) & 3;
  const int uq = lane & 3;
  float a[4][4];
#pragma unroll
  for (int i = 0; i < 4; ++i)
#pragma unroll
    for (int m = 0; m < 4; ++m) a[i][m] = 0.f;

#pragma unroll
  for (int it = 0; it < 3; ++it) {
    const int kli = it * 4 + kq;
    if (kli < 9) {
      const int kl = w * 9 + kli;
      const float ck = sc[kl];
      float4 xa[4], xb[4];
#pragma unroll
      for (int i = 0; i < 4; ++i) {
        const float* xr = sx + (bq * 4 + i) * XPB + kl * 8;
        xa[i] = *(const float4*)xr;
        xb[i] = *(const float4*)(xr + 4);
      }
      float4 wa[4], wb[4];
      const float* wr = sw + kl * WKP + 36 * uq;  // u = 4*uq+m at +8m
#pragma unroll
      for (int m = 0; m < 4; ++m) {
        wa[m] = *(const float4*)(wr + 8 * m);
        wb[m] = *(const float4*)(wr + 8 * m + 4);
      }
#pragma unroll
      for (int i = 0; i < 4; ++i)
#pragma unroll
        for (int m = 0; m < 4; ++m) {
          const float dot =
              xa[i].x * wa[m].x + xa[i].y * wa[m].y + xa[i].z * wa[m].z +
              xa[i].w * wa[m].w + xb[i].x * wb[m].x + xb[i].y * wb[m].y +
              xb[i].z * wb[m].z + xb[i].w * wb[m].w;
          a[i][m] = fmaf(ck, dot, a[i][m]);
        }
    }
  }
  // reduce over kq (lane bits 4,5)
#pragma unroll
  for (int i = 0; i < 4; ++i)
#pragma unroll
    for (int m = 0; m < 4; ++m) {
      a[i][m] += __shfl_xor(a[i][m], 16, 64);
      a[i][m] += __shfl_xor(a[i][m], 32, 64);
    }
  __syncthreads();  // everyone done reading sx; safe to reuse as sred
  if (kq == 0) {    // 16 lanes (bq,uq) hold the wave's 16b x 16u tile
#pragma unroll
    for (int i = 0; i < 4; ++i) {
      const float4 t4 = {a[i][0], a[i][1], a[i][2], a[i][3]};
      *(float4*)&sred[(w * BT + bq * 4 + i) * SREDP + uq * 4] = t4;
    }
  }
  __syncthreads();
  {  // sum the 4 waves' k-ranges, write partial (coalesced)
    const int b = tid >> 4, u = tid & 15;
    const float s =
        sred[(0 * BT + b) * SREDP + u] + sred[(1 * BT + b) * SREDP + u] +
        sred[(2 * BT + b) * SREDP + u] + sred[(3 * BT + b) * SREDP + u];
    partial[(size_t)kc * (NB * NU) + (size_t)(b0 + b) * NU + u] = s;
  }
}

// ---------------------------------------------------------------------------
// caps_agp: block (kc,bgi). Recomputes v = squash(sum_kc partial) for its 16 b
// (writes out[:,ja,:] from kc==0 blocks when wout), then agree for column ja:
// atomicAdd(&bl[k][ja], sum_{b,u} uhat*v).
// Wave w owns k = w*9..+8; lane = (bq = lane>>4: 4 b's, u = lane&15).
// ---------------------------------------------------------------------------
__global__ __launch_bounds__(256, 4) void caps_agp(
    const float* __restrict__ x, const float* __restrict__ WT,
    const float* __restrict__ partial, float* __restrict__ bl,
    float* __restrict__ out, int ja, int wout) {
  __shared__ float smem2[KT * XPK + KT * WKP + BT * SVP];  // 40320 B: 4/CU
  float* sxA = smem2;                 // [k][b*8+d] pitch 132
  float* sw = smem2 + KT * XPK;       // [k][u-swizzled] pitch 140
  float* sv = smem2 + KT * XPK + KT * WKP;  // [b][u] pitch 18
  const int tid = threadIdx.x;
  const int kc = blockIdx.x & (KCN - 1);
  const int bgi = blockIdx.x >> 5;
  const int b0 = bgi * BT;
  const int k0 = kc * KT;

  {  // stage x transposed: [k][b]
    const float4* gx = (const float4*)(x + (size_t)b0 * (NK * ND) + k0 * ND);
    for (int i = tid; i < BT * 72; i += 256) {
      const int b = i / 72, q = i - b * 72;
      const float4 vx = gx[(size_t)b * (NK * ND / 4) + q];
      *(float4*)&sxA[(q >> 1) * XPK + b * 8 + (q & 1) * 4] = vx;
    }
  }
  {  // stage w for column ja
    const float4* gw = (const float4*)(WT + ((size_t)ja * NK + k0) * (NU * ND));
    for (int i = tid; i < KT * 32; i += 256) {
      const int k = i >> 5, r = i & 31;
      const int u = r >> 1, h = r & 1;
      const float4 vw = gw[i];
      *(float4*)&sw[k * WKP + WOFF(u) + h * 4] = vw;
    }
  }
  {  // v = squash(sum of 32 partials); wave = 4b x 16u, u = low 4 lane bits
    const int b = tid >> 4, u = tid & 15;
    const float* pp = partial + (size_t)(b0 + b) * NU + u;
    float s = 0.f;
#pragma unroll
    for (int c = 0; c < KCN; ++c) s += pp[(size_t)c * (NB * NU)];
    float sq = s * s;
    sq += __shfl_xor(sq, 1, 64);
    sq += __shfl_xor(sq, 2, 64);
    sq += __shfl_xor(sq, 4, 64);
    sq += __shfl_xor(sq, 8, 64);
    const float scale = (sq / (1.f + sq)) / (sqrtf(sq) + EPSQ);
    const float vv = scale * s;
    sv[b * SVP + u] = vv;
    if (wout && kc == 0) out[((size_t)(b0 + b) * NJ + ja) * NU + u] = vv;
  }
  __syncthreads();

  const int w = tid >> 6;
  const int lane = tid & 63;
  const int bq = lane >> 4;
  const int u = lane & 15;
  for (int kk = 0; kk < 9; ++kk) {
    const int kloc = w * 9 + kk;
    const float* wr = sw + kloc * WKP + WOFF(u);
    const float4 wa = *(const float4*)wr;
    const float4 wb = *(const float4*)(wr + 4);
    float ag = 0.f;
#pragma unroll
    for (int i = 0; i < 4; ++i) {
      const int b = bq * 4 + i;
      const float* xr = sxA + kloc * XPK + b * 8;
      const float4 xa = *(const float4*)xr;
      const float4 xb = *(const float4*)(xr + 4);
      const float dot = xa.x * wa.x + xa.y * wa.y + xa.z * wa.z +
                        xa.w * wa.w + xb.x * wb.x + xb.y * wb.y +
                        xb.z * wb.z + xb.w * wb.w;
      ag = fmaf(sv[b * SVP + u], dot, ag);
    }
    ag += __shfl_xor(ag, 1, 64);   // over u
    ag += __shfl_xor(ag, 2, 64);
    ag += __shfl_xor(ag, 4, 64);
    ag += __shfl_xor(ag, 8, 64);
    ag += __shfl_xor(ag, 16, 64);  // over bq
    ag += __shfl_xor(ag, 32, 64);
    if (lane == 0)  // one atomic per k per block; visible next kernel
      atomicAdd(&bl[(size_t)(k0 + kloc) * NJ + ja], ag);
  }
}

// ---------------------------------------------------------------------------
// caps_finout: final v for capsule 9 -> out[:, 9, :]
// ---------------------------------------------------------------------------
__global__ __launch_bounds__(256) void caps_finout(const float* __restrict__ partial,
                                                   float* __restrict__ out) {
  const int g = blockIdx.x * 256 + threadIdx.x;  // 8192
  const int b = g >> 4, u = g & 15;
  float s = 0.f;
#pragma unroll
  for (int c = 0; c < KCN; ++c)
    s += partial[(size_t)c * (NB * NU) + (size_t)b * NU + u];
  float sq = s * s;
  sq += __shfl_xor(sq, 1, 64);
  sq += __shfl_xor(sq, 2, 64);
  sq += __shfl_xor(sq, 4, 64);
  sq += __shfl_xor(sq, 8, 64);
  const float scale = (sq / (1.f + sq)) / (sqrtf(sq) + EPSQ);
  out[((size_t)b * NJ + (NJ - 1)) * NU + u] = scale * s;
}

// ---------------------------------------------------------------------------
extern "C" void kernel_launch(void* const* d_in, const int* in_sizes, int n_in,
                              void* d_out, int out_size, void* d_ws,
                              size_t ws_size, hipStream_t stream) {
  (void)in_sizes; (void)n_in; (void)out_size; (void)ws_size;
  const float* x = (const float*)d_in[0];   // [512][1152][8][1] fp32
  const float* W = (const float*)d_in[1];   // [10][1152][8][16] fp32
  float* out = (float*)d_out;               // [512][10][16][1] fp32
  float* ws = (float*)d_ws;
  float* bl = ws + OFF_BL;
  float* pt = ws + OFF_P;
  float* WT = ws + OFF_WT;

  caps_init<<<(WT_FLOATS + 255) / 256, 256, 0, stream>>>(W, bl, WT);
  for (int n = 0; n < NJ * 3; ++n) {
    const int j = n / 3, t = n - 3 * j;
    if (n > 0) {
      // agree for iteration n-1: capsule ja = (t==0 ? j-1 : j); t==0 also
      // emits the final v of capsule j-1 to out (kc==0 blocks).
      const int ja = (t == 0) ? (j - 1) : j;
      caps_agp<<<KCN * BGN, 256, 0, stream>>>(x, WT, pt, bl, out, ja,
                                              (t == 0) ? 1 : 0);
    }
    caps_part<<<KCN * BGN, 256, 0, stream>>>(x, WT, bl, pt, j);
  }
  caps_finout<<<(NB * NU) / 256, 256, 0, stream>>>(pt, out);
}

// Round 10
// 526.153 us; speedup vs baseline: 7.4472x; 1.2786x over previous
//
#include <hip/hip_runtime.h>

#define NB 512      // batch
#define NK 1152     // input capsules
#define ND 8        // in dim
#define NU 16       // out dim
#define NJ 10       // output capsules
#define NPH 30      // routing phases (NJ * 3)
#define EPSQ 1e-7f

#define KT 36       // k per tile
#define KCN 32      // k chunks (KT*KCN == NK); kc = blockIdx&31 -> XCD = kc%8
#define BT 16       // b per tile
#define BGN 32      // b groups (BT*BGN == NB)
#define XPB 292     // x pitch per b (36k*8 + 4)
#define WKP 140     // w pitch per k (swizzle span 140 — R8 lesson: not less!)
#define SREDP 20    // part cross-wave reduce pitch
#define SVP 20      // agp sv pitch (b128-aligned: 18 breaks alignment)
// u-pair swizzle: pair p=(u>>1) base = 16p+4*(p>>1); odd u at +8.
// For u=4a+m: offset = 36a + 8m  (fragment hoist-friendly).
#define WOFF(u) ((((u) >> 1) << 4) + (((u) >> 2) << 2) + (((u) & 1) << 3))

// ws layout (floats); harness ws (~268 MB) >> 7 MB needed
#define OFF_BL 0                       // b_logits [NK][NJ]      11520
#define OFF_S  11520                   // s [NPH][NB][NU]        245760
#define OFF_WT (OFF_S + NPH*NB*NU)     // WT [NJ][NK][NU][ND]
#define WT_FLOATS (NJ*NK*NU*ND)        // 1474560

// ---------------------------------------------------------------------------
// init: zero b_logits + all 30 phase s-buffers, build WT[j][k][u][d]
// ---------------------------------------------------------------------------
__global__ __launch_bounds__(256) void caps_init(const float* __restrict__ W,
                                                 float* __restrict__ bl,
                                                 float* __restrict__ s,
                                                 float* __restrict__ WT) {
  int idx = blockIdx.x * 256 + threadIdx.x;
  if (idx < NK * NJ) bl[idx] = 0.f;
  if (idx < NPH * NB * NU) s[idx] = 0.f;
  if (idx < WT_FLOATS) {
    int d = idx & 7;
    int u = (idx >> 3) & 15;
    int k = (idx >> 7) % NK;
    int j = idx / (NK * NU * ND);
    WT[idx] = W[((size_t)(j * NK + k) * ND + d) * NU + u];
  }
}

// ---------------------------------------------------------------------------
// caps_part: block (kc,bgi) = 16 b x 36 k tile. Softmax col js in-block, then
// atomicAdd into sn[b][u] += sum_{k in tile} c_k * (x[b,k,:]·W[js,k,:,u]).
// Wave w owns k = w*9..+8. Lane = (kq 4-way k-split, bq 4 b's, uq 4 u's).
// (R9-verified body; only the epilogue changed to atomic s-accumulation.)
// ---------------------------------------------------------------------------
__global__ __launch_bounds__(256, 4) void caps_part(
    const float* __restrict__ x, const float* __restrict__ WT,
    const float* __restrict__ bl, float* __restrict__ sn, int js) {
  __shared__ float smem[BT * XPB + KT * WKP + KT];  // 38.99 KB -> 4 blocks/CU
  float* sx = smem;                // [b][k*8+d] pitch 292
  float* sw = smem + BT * XPB;     // [k][u-swizzled] pitch 140
  float* sc = smem + BT * XPB + KT * WKP;
  float* sred = smem;              // aliases sx after compute (barrier-guarded)
  const int tid = threadIdx.x;
  const int kc = blockIdx.x & (KCN - 1);   // kc%8 == blockIdx%8 == XCD slot
  const int bgi = blockIdx.x >> 5;
  const int b0 = bgi * BT;
  const int k0 = kc * KT;

  {  // stage x: 16 b-rows x 72 float4 (coalesced)
    const float4* gx = (const float4*)(x + (size_t)b0 * (NK * ND) + k0 * ND);
    for (int i = tid; i < BT * 72; i += 256) {
      const int b = i / 72, q = i - b * 72;
      const float4 vx = gx[(size_t)b * (NK * ND / 4) + q];
      *(float4*)&sx[b * XPB + q * 4] = vx;
    }
  }
  {  // stage w: 36 k-rows x 32 float4 (contiguous in WT)
    const float4* gw = (const float4*)(WT + ((size_t)js * NK + k0) * (NU * ND));
    for (int i = tid; i < KT * 32; i += 256) {
      const int k = i >> 5, r = i & 31;
      const int u = r >> 1, h = r & 1;
      const float4 vw = gw[i];
      *(float4*)&sw[k * WKP + WOFF(u) + h * 4] = vw;
    }
  }
  if (tid < KT) {  // softmax of bl row (k0+tid), column js
    const float* row = bl + (size_t)(k0 + tid) * NJ;
    float r[NJ];
#pragma unroll
    for (int jj = 0; jj < NJ; ++jj) r[jj] = row[jj];
    float mx = r[0];
#pragma unroll
    for (int jj = 1; jj < NJ; ++jj) mx = fmaxf(mx, r[jj]);
    float se = 0.f;
#pragma unroll
    for (int jj = 0; jj < NJ; ++jj) se += __expf(r[jj] - mx);
    sc[tid] = __expf(r[js] - mx) / se;
  }
  __syncthreads();

  const int w = tid >> 6;
  const int lane = tid & 63;
  const int kq = lane >> 4;
  const int bq = (lane >> 2) & 3;
  const int uq = lane & 3;
  float a[4][4];
#pragma unroll
  for (int i = 0; i < 4; ++i)
#pragma unroll
    for (int m = 0; m < 4; ++m) a[i][m] = 0.f;

#pragma unroll
  for (int it = 0; it < 3; ++it) {
    const int kli = it * 4 + kq;
    if (kli < 9) {
      const int kl = w * 9 + kli;
      const float ck = sc[kl];
      float4 xa[4], xb[4];
#pragma unroll
      for (int i = 0; i < 4; ++i) {
        const float* xr = sx + (bq * 4 + i) * XPB + kl * 8;
        xa[i] = *(const float4*)xr;
        xb[i] = *(const float4*)(xr + 4);
      }
      float4 wa[4], wb[4];
      const float* wr = sw + kl * WKP + 36 * uq;  // u = 4*uq+m at +8m
#pragma unroll
      for (int m = 0; m < 4; ++m) {
        wa[m] = *(const float4*)(wr + 8 * m);
        wb[m] = *(const float4*)(wr + 8 * m + 4);
      }
#pragma unroll
      for (int i = 0; i < 4; ++i)
#pragma unroll
        for (int m = 0; m < 4; ++m) {
          const float dot =
              xa[i].x * wa[m].x + xa[i].y * wa[m].y + xa[i].z * wa[m].z +
              xa[i].w * wa[m].w + xb[i].x * wb[m].x + xb[i].y * wb[m].y +
              xb[i].z * wb[m].z + xb[i].w * wb[m].w;
          a[i][m] = fmaf(ck, dot, a[i][m]);
        }
    }
  }
  // reduce over kq (lane bits 4,5)
#pragma unroll
  for (int i = 0; i < 4; ++i)
#pragma unroll
    for (int m = 0; m < 4; ++m) {
      a[i][m] += __shfl_xor(a[i][m], 16, 64);
      a[i][m] += __shfl_xor(a[i][m], 32, 64);
    }
  __syncthreads();  // everyone done reading sx; safe to reuse as sred
  if (kq == 0) {    // 16 lanes (bq,uq) hold the wave's 16b x 16u tile
#pragma unroll
    for (int i = 0; i < 4; ++i) {
      const float4 t4 = {a[i][0], a[i][1], a[i][2], a[i][3]};
      *(float4*)&sred[(w * BT + bq * 4 + i) * SREDP + uq * 4] = t4;
    }
  }
  __syncthreads();
  {  // sum the 4 waves' k-ranges; accumulate into this phase's s buffer
    const int b = tid >> 4, u = tid & 15;
    const float sv =
        sred[(0 * BT + b) * SREDP + u] + sred[(1 * BT + b) * SREDP + u] +
        sred[(2 * BT + b) * SREDP + u] + sred[(3 * BT + b) * SREDP + u];
    atomicAdd(&sn[(size_t)(b0 + b) * NU + u], sv);
  }
}

// ---------------------------------------------------------------------------
// caps_agp: block (kc,bgi). v = squash(sprev[b]) (1 load/thread), write
// out[:,ja,:] from kc==0 when wout, then agree for column ja with part's
// 4b x 4u x kq microtile (v-fragment hoisted to registers):
// atomicAdd(&bl[k][ja], sum_{b,u} uhat[b,k,u]*v[b,u]).
// ---------------------------------------------------------------------------
__global__ __launch_bounds__(256, 4) void caps_agp(
    const float* __restrict__ x, const float* __restrict__ WT,
    const float* __restrict__ sprev, float* __restrict__ bl,
    float* __restrict__ out, int ja, int wout) {
  __shared__ float smem2[BT * XPB + KT * WKP + BT * SVP];  // 40128 B: 4/CU
  float* sx = smem2;                  // [b][k*8+d] pitch 292 (same as part)
  float* sw = smem2 + BT * XPB;       // [k][u-swizzled] pitch 140
  float* sv = smem2 + BT * XPB + KT * WKP;  // [b][u] pitch 20
  const int tid = threadIdx.x;
  const int kc = blockIdx.x & (KCN - 1);
  const int bgi = blockIdx.x >> 5;
  const int b0 = bgi * BT;
  const int k0 = kc * KT;

  {  // stage x: identical to part (coalesced, b-major)
    const float4* gx = (const float4*)(x + (size_t)b0 * (NK * ND) + k0 * ND);
    for (int i = tid; i < BT * 72; i += 256) {
      const int b = i / 72, q = i - b * 72;
      const float4 vx = gx[(size_t)b * (NK * ND / 4) + q];
      *(float4*)&sx[b * XPB + q * 4] = vx;
    }
  }
  {  // stage w for column ja
    const float4* gw = (const float4*)(WT + ((size_t)ja * NK + k0) * (NU * ND));
    for (int i = tid; i < KT * 32; i += 256) {
      const int k = i >> 5, r = i & 31;
      const int u = r >> 1, h = r & 1;
      const float4 vw = gw[i];
      *(float4*)&sw[k * WKP + WOFF(u) + h * 4] = vw;
    }
  }
  {  // v = squash(s) from the pre-accumulated phase buffer (1 load/thread)
    const int b = tid >> 4, u = tid & 15;   // u = lane bits 0-3
    const float s = sprev[(size_t)(b0 + b) * NU + u];
    float sq = s * s;
    sq += __shfl_xor(sq, 1, 64);
    sq += __shfl_xor(sq, 2, 64);
    sq += __shfl_xor(sq, 4, 64);
    sq += __shfl_xor(sq, 8, 64);
    const float scale = (sq / (1.f + sq)) / (sqrtf(sq) + EPSQ);
    const float vv = scale * s;
    sv[b * SVP + u] = vv;
    if (wout && kc == 0) out[((size_t)(b0 + b) * NJ + ja) * NU + u] = vv;
  }
  __syncthreads();

  const int w = tid >> 6;
  const int lane = tid & 63;
  const int kq = lane >> 4;
  const int bq = (lane >> 2) & 3;
  const int uq = lane & 3;
  // hoist v fragment: [4 b][4 u] = 16 floats in registers (const across k)
  float4 vf[4];
#pragma unroll
  for (int i = 0; i < 4; ++i)
    vf[i] = *(const float4*)&sv[(bq * 4 + i) * SVP + uq * 4];

#pragma unroll
  for (int it = 0; it < 3; ++it) {
    const int kli = it * 4 + kq;
    if (kli < 9) {
      const int kl = w * 9 + kli;
      float4 xa[4], xb[4];
#pragma unroll
      for (int i = 0; i < 4; ++i) {
        const float* xr = sx + (bq * 4 + i) * XPB + kl * 8;
        xa[i] = *(const float4*)xr;
        xb[i] = *(const float4*)(xr + 4);
      }
      float4 wa[4], wb[4];
      const float* wr = sw + kl * WKP + 36 * uq;
#pragma unroll
      for (int m = 0; m < 4; ++m) {
        wa[m] = *(const float4*)(wr + 8 * m);
        wb[m] = *(const float4*)(wr + 8 * m + 4);
      }
      float ag = 0.f;
#pragma unroll
      for (int i = 0; i < 4; ++i) {
        const float4 v4 = vf[i];
        float d0 = xa[i].x * wa[0].x + xa[i].y * wa[0].y + xa[i].z * wa[0].z +
                   xa[i].w * wa[0].w + xb[i].x * wb[0].x + xb[i].y * wb[0].y +
                   xb[i].z * wb[0].z + xb[i].w * wb[0].w;
        float d1 = xa[i].x * wa[1].x + xa[i].y * wa[1].y + xa[i].z * wa[1].z +
                   xa[i].w * wa[1].w + xb[i].x * wb[1].x + xb[i].y * wb[1].y +
                   xb[i].z * wb[1].z + xb[i].w * wb[1].w;
        float d2 = xa[i].x * wa[2].x + xa[i].y * wa[2].y + xa[i].z * wa[2].z +
                   xa[i].w * wa[2].w + xb[i].x * wb[2].x + xb[i].y * wb[2].y +
                   xb[i].z * wb[2].z + xb[i].w * wb[2].w;
        float d3 = xa[i].x * wa[3].x + xa[i].y * wa[3].y + xa[i].z * wa[3].z +
                   xa[i].w * wa[3].w + xb[i].x * wb[3].x + xb[i].y * wb[3].y +
                   xb[i].z * wb[3].z + xb[i].w * wb[3].w;
        ag = fmaf(v4.x, d0, ag);
        ag = fmaf(v4.y, d1, ag);
        ag = fmaf(v4.z, d2, ag);
        ag = fmaf(v4.w, d3, ag);
      }
      // reduce over (bq,uq) = lane bits 0-3 (stays within the kq group)
      ag += __shfl_xor(ag, 1, 64);
      ag += __shfl_xor(ag, 2, 64);
      ag += __shfl_xor(ag, 4, 64);
      ag += __shfl_xor(ag, 8, 64);
      if ((lane & 15) == 0)  // one atomic per k per block
        atomicAdd(&bl[(size_t)(k0 + kl) * NJ + ja], ag);
    }
  }
}

// ---------------------------------------------------------------------------
// caps_finout: final v for capsule 9 -> out[:, 9, :]  (from phase-29 s)
// ---------------------------------------------------------------------------
__global__ __launch_bounds__(256) void caps_finout(const float* __restrict__ slast,
                                                   float* __restrict__ out) {
  const int g = blockIdx.x * 256 + threadIdx.x;  // 8192
  const int b = g >> 4, u = g & 15;              // u = lane bits 0-3
  const float s = slast[(size_t)b * NU + u];
  float sq = s * s;
  sq += __shfl_xor(sq, 1, 64);
  sq += __shfl_xor(sq, 2, 64);
  sq += __shfl_xor(sq, 4, 64);
  sq += __shfl_xor(sq, 8, 64);
  const float scale = (sq / (1.f + sq)) / (sqrtf(sq) + EPSQ);
  out[((size_t)b * NJ + (NJ - 1)) * NU + u] = scale * s;
}

// ---------------------------------------------------------------------------
extern "C" void kernel_launch(void* const* d_in, const int* in_sizes, int n_in,
                              void* d_out, int out_size, void* d_ws,
                              size_t ws_size, hipStream_t stream) {
  (void)in_sizes; (void)n_in; (void)out_size; (void)ws_size;
  const float* x = (const float*)d_in[0];   // [512][1152][8][1] fp32
  const float* W = (const float*)d_in[1];   // [10][1152][8][16] fp32
  float* out = (float*)d_out;               // [512][10][16][1] fp32
  float* ws = (float*)d_ws;
  float* bl = ws + OFF_BL;
  float* s  = ws + OFF_S;                   // [NPH][NB][NU], zeroed by init
  float* WT = ws + OFF_WT;

  caps_init<<<(WT_FLOATS + 255) / 256, 256, 0, stream>>>(W, bl, s, WT);
  for (int n = 0; n < NPH; ++n) {
    const int j = n / 3, t = n - 3 * j;
    if (n > 0) {
      // agree for phase n-1: capsule ja = (t==0 ? j-1 : j); t==0 also emits
      // the final v of capsule j-1 (kc==0 blocks).
      const int ja = (t == 0) ? (j - 1) : j;
      caps_agp<<<KCN * BGN, 256, 0, stream>>>(x, WT, s + (size_t)(n - 1) * NB * NU,
                                              bl, out, ja, (t == 0) ? 1 : 0);
    }
    caps_part<<<KCN * BGN, 256, 0, stream>>>(x, WT, bl,
                                             s + (size_t)n * NB * NU, j);
  }
  caps_finout<<<(NB * NU) / 256, 256, 0, stream>>>(s + (size_t)(NPH - 1) * NB * NU,
                                                   out);
}

// Round 11
// 490.625 us; speedup vs baseline: 7.9865x; 1.0724x over previous
//
#include <hip/hip_runtime.h>

typedef unsigned int uint;
typedef unsigned short ushort_t;

#define NB 512      // batch
#define NK 1152     // input capsules
#define ND 8        // in dim
#define NU 16       // out dim
#define NJ 10       // output capsules
#define NPH 30      // routing phases (NJ * 3)
#define EPSQ 1e-7f

#define KT 36       // k per tile
#define KCN 32      // k chunks; kc = blockIdx&31 -> XCD = kc%8
#define BT 16       // b per tile
#define BGN 32      // b groups
#define XPH 296     // x tile pitch per b, in bf16 elems (288 + 8 pad -> 2-way banks)
#define WPH 136     // w tile pitch per k, in bf16 elems (128 + 8 pad -> 2-way banks)
#define SREDP 20    // part cross-wave reduce pitch (floats)
#define SVP 20      // agp sv pitch (floats, 16B-stride-aligned)

// ws layout (floats)
#define OFF_BL 0                        // b_logits [NK][NJ]      11520
#define OFF_S  11520                    // s [NPH][NB][NU]        245760
#define OFF_XB 257280                   // Xb bf16 [NB][NK][ND]   (2359296 floats)
#define OFF_WTB (OFF_XB + (NB*NK*ND)/2) // WTb bf16 [NJ][NK][NU][ND] (737280 floats)
// total ~13.4 MB << ws

// fp32 -> bf16 RNE (values are finite/normal here)
__device__ __forceinline__ ushort_t b16(float f) {
  uint u = __float_as_uint(f);
  return (ushort_t)((u + 0x7fffu + ((u >> 16) & 1u)) >> 16);
}
// unpack 8 bf16 (uint4) -> 8 fp32
__device__ __forceinline__ void up8(const uint4 v, float* f) {
  f[0] = __uint_as_float(v.x << 16); f[1] = __uint_as_float(v.x & 0xffff0000u);
  f[2] = __uint_as_float(v.y << 16); f[3] = __uint_as_float(v.y & 0xffff0000u);
  f[4] = __uint_as_float(v.z << 16); f[5] = __uint_as_float(v.z & 0xffff0000u);
  f[6] = __uint_as_float(v.w << 16); f[7] = __uint_as_float(v.w & 0xffff0000u);
}
__device__ __forceinline__ float dot8(const float* a, const float* b) {
  return a[0]*b[0] + a[1]*b[1] + a[2]*b[2] + a[3]*b[3] +
         a[4]*b[4] + a[5]*b[5] + a[6]*b[6] + a[7]*b[7];
}

// ---------------------------------------------------------------------------
// init: zero bl + s; build Xb[b][k][d] (bf16) and WTb[j][k][u][d] (bf16)
// ---------------------------------------------------------------------------
__global__ __launch_bounds__(256) void caps_init(const float* __restrict__ x,
                                                 const float* __restrict__ W,
                                                 float* __restrict__ bl,
                                                 float* __restrict__ s,
                                                 ushort_t* __restrict__ Xb,
                                                 ushort_t* __restrict__ WTb) {
  const int g = blockIdx.x * 256 + threadIdx.x;
  if (g < NK * NJ) bl[g] = 0.f;
  if (g < NPH * NB * NU) s[g] = 0.f;
  if (g < (NB * NK * ND) / 8) {  // 589824 groups of 8
    const float4* xp = (const float4*)x + (size_t)g * 2;
    const float4 a = xp[0], b = xp[1];
    uint4 o;
    o.x = (uint)b16(a.x) | ((uint)b16(a.y) << 16);
    o.y = (uint)b16(a.z) | ((uint)b16(a.w) << 16);
    o.z = (uint)b16(b.x) | ((uint)b16(b.y) << 16);
    o.w = (uint)b16(b.z) | ((uint)b16(b.w) << 16);
    ((uint4*)Xb)[g] = o;
  }
  if (g < (NJ * NK * NU * ND) / 8) {  // 184320 groups: (j,k,u) rows of 8 d
    const int u = g & 15;
    const int k = (g >> 4) % NK;
    const int j = g / (NK * NU);
    const float* wp = W + ((size_t)(j * NK + k) * ND) * NU + u;  // d-stride NU
    uint4 o;
    o.x = (uint)b16(wp[0])  | ((uint)b16(wp[16]) << 16);
    o.y = (uint)b16(wp[32]) | ((uint)b16(wp[48]) << 16);
    o.z = (uint)b16(wp[64]) | ((uint)b16(wp[80]) << 16);
    o.w = (uint)b16(wp[96]) | ((uint)b16(wp[112]) << 16);
    ((uint4*)WTb)[g] = o;
  }
}

// ---------------------------------------------------------------------------
// caps_part: block (kc,bgi) = 16 b x 36 k tile (bf16 LDS). Softmax col js,
// then atomicAdd sn[b][u] += sum_k c_k (x[b,k,:]·W[js,k,:,u]).
// Wave w owns k = w*9..+8; lane = (kq 4-way, bq 4 b's, uq 4 u's).
// ---------------------------------------------------------------------------
__global__ __launch_bounds__(256, 4) void caps_part(
    const ushort_t* __restrict__ Xb, const ushort_t* __restrict__ WTb,
    const float* __restrict__ bl, float* __restrict__ sn, int js) {
  __shared__ __align__(16) ushort_t sxu[BT * XPH];  // 9472 B [b][k*8+d]
  __shared__ __align__(16) ushort_t swu[KT * WPH];  // 9792 B [k][u*8+d]
  __shared__ float sc[KT];
  float* sred = (float*)sxu;  // aliased after compute (barrier-guarded), 5120 B
  const int tid = threadIdx.x;
  const int kc = blockIdx.x & (KCN - 1);
  const int bgi = blockIdx.x >> 5;
  const int b0 = bgi * BT;
  const int k0 = kc * KT;

  {  // stage x: 576 uint4 (one per (b,k)), coalesced 576B runs
    const uint4* gx = (const uint4*)Xb + ((size_t)b0 * NK + k0);
    for (int i = tid; i < BT * KT; i += 256) {
      const int b = i / KT, q = i - b * KT;
      const uint4 v = gx[(size_t)b * NK + q];
      *(uint4*)&sxu[b * XPH + q * 8] = v;
    }
  }
  {  // stage w: 576 uint4 (one per (k,u)), contiguous in WTb
    const uint4* gw = (const uint4*)WTb + ((size_t)js * NK + k0) * NU;
    for (int i = tid; i < KT * NU; i += 256) {
      const int k = i >> 4, u = i & 15;
      const uint4 v = gw[i];
      *(uint4*)&swu[k * WPH + u * 8] = v;
    }
  }
  if (tid < KT) {  // softmax of bl row (k0+tid), column js
    const float* row = bl + (size_t)(k0 + tid) * NJ;
    float r[NJ];
#pragma unroll
    for (int jj = 0; jj < NJ; ++jj) r[jj] = row[jj];
    float mx = r[0];
#pragma unroll
    for (int jj = 1; jj < NJ; ++jj) mx = fmaxf(mx, r[jj]);
    float se = 0.f;
#pragma unroll
    for (int jj = 0; jj < NJ; ++jj) se += __expf(r[jj] - mx);
    sc[tid] = __expf(r[js] - mx) / se;
  }
  __syncthreads();

  const int w = tid >> 6;
  const int lane = tid & 63;
  const int kq = lane >> 4;
  const int bq = (lane >> 2) & 3;
  const int uq = lane & 3;
  float a[4][4];
#pragma unroll
  for (int i = 0; i < 4; ++i)
#pragma unroll
    for (int m = 0; m < 4; ++m) a[i][m] = 0.f;

#pragma unroll
  for (int it = 0; it < 3; ++it) {
    const int kli = it * 4 + kq;
    if (kli < 9) {
      const int kl = w * 9 + kli;
      const float ck = sc[kl];
      float xd[4][8];
#pragma unroll
      for (int i = 0; i < 4; ++i) {
        const uint4 xv = *(const uint4*)&sxu[(bq * 4 + i) * XPH + kl * 8];
        up8(xv, xd[i]);
      }
#pragma unroll
      for (int m = 0; m < 4; ++m) {
        const uint4 wv = *(const uint4*)&swu[kl * WPH + (uq * 4 + m) * 8];
        float wd[8];
        up8(wv, wd);
#pragma unroll
        for (int i = 0; i < 4; ++i)
          a[i][m] = fmaf(ck, dot8(xd[i], wd), a[i][m]);
      }
    }
  }
  // reduce over kq (lane bits 4,5)
#pragma unroll
  for (int i = 0; i < 4; ++i)
#pragma unroll
    for (int m = 0; m < 4; ++m) {
      a[i][m] += __shfl_xor(a[i][m], 16, 64);
      a[i][m] += __shfl_xor(a[i][m], 32, 64);
    }
  __syncthreads();  // sx dead; reuse as sred
  if (kq == 0) {
#pragma unroll
    for (int i = 0; i < 4; ++i) {
      const float4 t4 = {a[i][0], a[i][1], a[i][2], a[i][3]};
      *(float4*)&sred[(w * BT + bq * 4 + i) * SREDP + uq * 4] = t4;
    }
  }
  __syncthreads();
  {  // sum 4 waves; accumulate into this phase's s buffer
    const int b = tid >> 4, u = tid & 15;
    const float sv =
        sred[(0 * BT + b) * SREDP + u] + sred[(1 * BT + b) * SREDP + u] +
        sred[(2 * BT + b) * SREDP + u] + sred[(3 * BT + b) * SREDP + u];
    atomicAdd(&sn[(size_t)(b0 + b) * NU + u], sv);
  }
}

// ---------------------------------------------------------------------------
// caps_agp: v = squash(sprev[b]) (1 load/thread; out write from kc==0 when
// wout), then agree for column ja with the same 4b x 4u x kq microtile:
// atomicAdd(&bl[k][ja], sum_{b,u} uhat[b,k,u]*v[b,u]).
// ---------------------------------------------------------------------------
__global__ __launch_bounds__(256, 4) void caps_agp(
    const ushort_t* __restrict__ Xb, const ushort_t* __restrict__ WTb,
    const float* __restrict__ sprev, float* __restrict__ bl,
    float* __restrict__ out, int ja, int wout) {
  __shared__ __align__(16) ushort_t sxu[BT * XPH];
  __shared__ __align__(16) ushort_t swu[KT * WPH];
  __shared__ float sv[BT * SVP];
  const int tid = threadIdx.x;
  const int kc = blockIdx.x & (KCN - 1);
  const int bgi = blockIdx.x >> 5;
  const int b0 = bgi * BT;
  const int k0 = kc * KT;

  {  // stage x
    const uint4* gx = (const uint4*)Xb + ((size_t)b0 * NK + k0);
    for (int i = tid; i < BT * KT; i += 256) {
      const int b = i / KT, q = i - b * KT;
      const uint4 v = gx[(size_t)b * NK + q];
      *(uint4*)&sxu[b * XPH + q * 8] = v;
    }
  }
  {  // stage w for column ja
    const uint4* gw = (const uint4*)WTb + ((size_t)ja * NK + k0) * NU;
    for (int i = tid; i < KT * NU; i += 256) {
      const int k = i >> 4, u = i & 15;
      const uint4 v = gw[i];
      *(uint4*)&swu[k * WPH + u * 8] = v;
    }
  }
  {  // v = squash(s); wave = 4b x 16u, u = low 4 lane bits
    const int b = tid >> 4, u = tid & 15;
    const float s = sprev[(size_t)(b0 + b) * NU + u];
    float sq = s * s;
    sq += __shfl_xor(sq, 1, 64);
    sq += __shfl_xor(sq, 2, 64);
    sq += __shfl_xor(sq, 4, 64);
    sq += __shfl_xor(sq, 8, 64);
    const float scale = (sq / (1.f + sq)) / (sqrtf(sq) + EPSQ);
    const float vv = scale * s;
    sv[b * SVP + u] = vv;
    if (wout && kc == 0) out[((size_t)(b0 + b) * NJ + ja) * NU + u] = vv;
  }
  __syncthreads();

  const int w = tid >> 6;
  const int lane = tid & 63;
  const int kq = lane >> 4;
  const int bq = (lane >> 2) & 3;
  const int uq = lane & 3;
  float4 vf[4];  // v fragment [4 b][4 u], const across k
#pragma unroll
  for (int i = 0; i < 4; ++i)
    vf[i] = *(const float4*)&sv[(bq * 4 + i) * SVP + uq * 4];

#pragma unroll
  for (int it = 0; it < 3; ++it) {
    const int kli = it * 4 + kq;
    if (kli < 9) {
      const int kl = w * 9 + kli;
      float xd[4][8];
#pragma unroll
      for (int i = 0; i < 4; ++i) {
        const uint4 xv = *(const uint4*)&sxu[(bq * 4 + i) * XPH + kl * 8];
        up8(xv, xd[i]);
      }
      float ag = 0.f;
#pragma unroll
      for (int m = 0; m < 4; ++m) {
        const uint4 wv = *(const uint4*)&swu[kl * WPH + (uq * 4 + m) * 8];
        float wd[8];
        up8(wv, wd);
#pragma unroll
        for (int i = 0; i < 4; ++i) {
          const float vm = (m == 0) ? vf[i].x
                         : (m == 1) ? vf[i].y
                         : (m == 2) ? vf[i].z : vf[i].w;
          ag = fmaf(vm, dot8(xd[i], wd), ag);
        }
      }
      // reduce over (bq,uq) = lane bits 0-3 (stays within the kq group)
      ag += __shfl_xor(ag, 1, 64);
      ag += __shfl_xor(ag, 2, 64);
      ag += __shfl_xor(ag, 4, 64);
      ag += __shfl_xor(ag, 8, 64);
      if ((lane & 15) == 0)
        atomicAdd(&bl[(size_t)(k0 + kl) * NJ + ja], ag);
    }
  }
}

// ---------------------------------------------------------------------------
// caps_finout: final v for capsule 9 -> out[:, 9, :]  (from phase-29 s)
// ---------------------------------------------------------------------------
__global__ __launch_bounds__(256) void caps_finout(const float* __restrict__ slast,
                                                   float* __restrict__ out) {
  const int g = blockIdx.x * 256 + threadIdx.x;  // 8192
  const int b = g >> 4, u = g & 15;
  const float s = slast[(size_t)b * NU + u];
  float sq = s * s;
  sq += __shfl_xor(sq, 1, 64);
  sq += __shfl_xor(sq, 2, 64);
  sq += __shfl_xor(sq, 4, 64);
  sq += __shfl_xor(sq, 8, 64);
  const float scale = (sq / (1.f + sq)) / (sqrtf(sq) + EPSQ);
  out[((size_t)b * NJ + (NJ - 1)) * NU + u] = scale * s;
}

// ---------------------------------------------------------------------------
extern "C" void kernel_launch(void* const* d_in, const int* in_sizes, int n_in,
                              void* d_out, int out_size, void* d_ws,
                              size_t ws_size, hipStream_t stream) {
  (void)in_sizes; (void)n_in; (void)out_size; (void)ws_size;
  const float* x = (const float*)d_in[0];   // [512][1152][8][1] fp32
  const float* W = (const float*)d_in[1];   // [10][1152][8][16] fp32
  float* out = (float*)d_out;               // [512][10][16][1] fp32
  float* ws = (float*)d_ws;
  float* bl = ws + OFF_BL;
  float* s  = ws + OFF_S;                   // [NPH][NB][NU], zeroed by init
  ushort_t* Xb  = (ushort_t*)(ws + OFF_XB);
  ushort_t* WTb = (ushort_t*)(ws + OFF_WTB);

  caps_init<<<(NB * NK * ND / 8 + 255) / 256, 256, 0, stream>>>(x, W, bl, s,
                                                                Xb, WTb);
  for (int n = 0; n < NPH; ++n) {
    const int j = n / 3, t = n - 3 * j;
    if (n > 0) {
      // agree for phase n-1: capsule ja = (t==0 ? j-1 : j); t==0 also emits
      // the final v of capsule j-1 (kc==0 blocks).
      const int ja = (t == 0) ? (j - 1) : j;
      caps_agp<<<KCN * BGN, 256, 0, stream>>>(
          Xb, WTb, s + (size_t)(n - 1) * NB * NU, bl, out, ja, (t == 0) ? 1 : 0);
    }
    caps_part<<<KCN * BGN, 256, 0, stream>>>(Xb, WTb, bl,
                                             s + (size_t)n * NB * NU, j);
  }
  caps_finout<<<(NB * NU) / 256, 256, 0, stream>>>(
      s + (size_t)(NPH - 1) * NB * NU, out);
}